// Round 1
// baseline (911.042 us; speedup 1.0000x reference)
//
#include <hip/hip_runtime.h>
#include <hip/hip_bf16.h>
#include <stdint.h>
#include <math.h>

#define BB 2
#define CC 512
#define HH 64
#define WW 64
#define LL 4096
#define DD 256
#define CIN 4608   // 512*9

// ---------------- Kernel 0: transpose W [256][4608] -> Wt [4608][256]
__global__ __launch_bounds__(256) void transposeW(const float* __restrict__ Wsrc,
                                                  float* __restrict__ Wt) {
    __shared__ float tile[32][33];
    int bx = blockIdx.x;            // CIN/32 = 144
    int by = blockIdx.y;            // D/32 = 8
    int tx = threadIdx.x & 31;
    int ty = threadIdx.x >> 5;      // 0..7
#pragma unroll
    for (int i = 0; i < 4; i++) {
        int d = by * 32 + ty + i * 8;
        int k = bx * 32 + tx;
        tile[ty + i * 8][tx] = Wsrc[(size_t)d * CIN + k];
    }
    __syncthreads();
#pragma unroll
    for (int i = 0; i < 4; i++) {
        int k = bx * 32 + ty + i * 8;
        int d = by * 32 + tx;
        Wt[(size_t)k * DD + d] = tile[tx][ty + i * 8];
    }
}

// ---------------- Kernel 1: embed (implicit unfold GEMM) + D-norm, fp32
// out tile: 256 (d) x 32 (l) per block.  grid (128 l-tiles, 4 images)
#define BK1 32
#define BN1 32
__global__ __launch_bounds__(256) void embed_norm(const float* __restrict__ query,
                                                  const float* __restrict__ key,
                                                  const float* __restrict__ Wt,
                                                  float* __restrict__ q_n,
                                                  float* __restrict__ k_n) {
    __shared__ float sW[BK1][DD];      // 32 KB  [kk][d]
    __shared__ float sU[BK1][40];      // 5 KB   [kk][x] (pad 40: 160B rows, 16B aligned)
    __shared__ float red[16][BN1];
    __shared__ float invn[BN1];

    int iid = blockIdx.y;              // 0..3
    int b = iid & 1, type = iid >> 1;  // type 0 = query, 1 = key
    const float* img = (type ? key : query) + (size_t)b * CC * LL;
    int bx = blockIdx.x;               // 0..127
    int y  = bx >> 1;
    int x0 = (bx & 1) * 32;
    int t  = threadIdx.x;
    int tr = t >> 4, tc = t & 15;      // rows tr*16+i, cols tc*2+j

    float acc[16][2];
#pragma unroll
    for (int i = 0; i < 16; i++) { acc[i][0] = 0.f; acc[i][1] = 0.f; }

    for (int k0 = 0; k0 < CIN; k0 += BK1) {
        // W tile: 32 rows x 256 d  (coalesced f4, linear LDS)
        const float4* wsrc = (const float4*)(Wt + (size_t)k0 * DD);
        float4* wdst = (float4*)&sW[0][0];
#pragma unroll
        for (int u = 0; u < 8; u++) wdst[u * 256 + t] = wsrc[u * 256 + t];
        // U tile (implicit unfold): kk -> (c,di,dj)
        {
            int kk = t >> 3;           // 0..31
            int xg = t & 7;            // 0..7
            int k = k0 + kk;
            int c = k / 9;
            int r = k - c * 9;
            int di = r / 3, dj = r - di * 3;
            int yy = y + di - 1;
            const float* row = img + (size_t)c * LL + yy * WW;
            float tmp[4];
#pragma unroll
            for (int u = 0; u < 4; u++) {
                int xx = x0 + xg * 4 + u + dj - 1;
                tmp[u] = (yy >= 0 && yy < HH && xx >= 0 && xx < WW) ? row[xx] : 0.f;
            }
            *(float4*)&sU[kk][xg * 4] = make_float4(tmp[0], tmp[1], tmp[2], tmp[3]);
        }
        __syncthreads();
#pragma unroll 4
        for (int kk = 0; kk < BK1; kk++) {
            float4 a0 = *(const float4*)&sW[kk][tr * 16 + 0];
            float4 a1 = *(const float4*)&sW[kk][tr * 16 + 4];
            float4 a2 = *(const float4*)&sW[kk][tr * 16 + 8];
            float4 a3 = *(const float4*)&sW[kk][tr * 16 + 12];
            float2 bv = *(const float2*)&sU[kk][tc * 2];
            float a[16] = {a0.x,a0.y,a0.z,a0.w, a1.x,a1.y,a1.z,a1.w,
                           a2.x,a2.y,a2.z,a2.w, a3.x,a3.y,a3.z,a3.w};
#pragma unroll
            for (int i = 0; i < 16; i++) {
                acc[i][0] += a[i] * bv.x;
                acc[i][1] += a[i] * bv.y;
            }
        }
        __syncthreads();
    }

    // ---- normalize along d (full 256 in this block)
    float ss0 = 0.f, ss1 = 0.f;
#pragma unroll
    for (int i = 0; i < 16; i++) { ss0 += acc[i][0] * acc[i][0]; ss1 += acc[i][1] * acc[i][1]; }
    red[tr][tc * 2 + 0] = ss0;
    red[tr][tc * 2 + 1] = ss1;
    __syncthreads();
    if (t < 32) {
        float s = 0.f;
#pragma unroll
        for (int r = 0; r < 16; r++) s += red[r][t];
        invn[t] = 1.0f / fmaxf(sqrtf(s), 1e-12f);
    }
    __syncthreads();
    float in0 = invn[tc * 2 + 0], in1 = invn[tc * 2 + 1];
#pragma unroll
    for (int i = 0; i < 16; i++) { acc[i][0] *= in0; acc[i][1] *= in1; }

    int lbase = y * WW + x0 + tc * 2;
    if (type == 0) {
        // q_n: [b][d][L]
        float* qb = q_n + (size_t)b * DD * LL;
#pragma unroll
        for (int i = 0; i < 16; i++) {
            int d = tr * 16 + i;
            *(float2*)&qb[(size_t)d * LL + lbase] = make_float2(acc[i][0], acc[i][1]);
        }
    } else {
        // k_n: [b][L][d]
#pragma unroll
        for (int j = 0; j < 2; j++) {
            float* dst = k_n + ((size_t)b * LL + lbase + j) * DD + tr * 16;
#pragma unroll
            for (int u = 0; u < 4; u++)
                *(float4*)&dst[u * 4] = make_float4(acc[4*u+0][j], acc[4*u+1][j],
                                                    acc[4*u+2][j], acc[4*u+3][j]);
        }
    }
}

// ---------------- Kernel 2: init packed max buffer
__global__ void init_packed(unsigned long long* p, int n) {
    int i = blockIdx.x * 256 + threadIdx.x;
    if (i < n) p[i] = 0ull;
}

// ---------------- Kernel 3: corr GEMM + fused column max/argmax
// corr[l,m] = sum_d k_n[l,d] * q_n[d,m];  per-m max over l via packed atomicMax
#define BM2 64
#define BN2 64
#define BK2 32
__global__ __launch_bounds__(256) void corr_max(const float* __restrict__ k_n,
                                                const float* __restrict__ q_n,
                                                unsigned long long* __restrict__ packed) {
    __shared__ float sA[BK2][68];                // [kk][l-row], pad 68 (272B rows)
    __shared__ float sB[BK2][BN2];               // [kk][m-col]
    __shared__ unsigned long long red[16][64];

    int b  = blockIdx.z;
    int l0 = blockIdx.y * BM2;
    int m0 = blockIdx.x * BN2;
    int t  = threadIdx.x;
    int tr = t >> 4, tc = t & 15;                // rows tr*4+i, cols tc*4+j

    const float* A  = k_n + (size_t)b * LL * DD; // [L][D]
    const float* Bq = q_n + (size_t)b * DD * LL; // [D][L]

    float acc[4][4];
#pragma unroll
    for (int i = 0; i < 4; i++)
#pragma unroll
        for (int j = 0; j < 4; j++) acc[i][j] = 0.f;

    for (int k0 = 0; k0 < DD; k0 += BK2) {
        {
            int r  = t >> 3;            // 0..31
            int kg = (t & 7) * 4;       // 0..28
#pragma unroll
            for (int p = 0; p < 2; p++) {
                int rr = r + p * 32;
                float4 v = *(const float4*)&A[(size_t)(l0 + rr) * DD + k0 + kg];
                sA[kg + 0][rr] = v.x; sA[kg + 1][rr] = v.y;
                sA[kg + 2][rr] = v.z; sA[kg + 3][rr] = v.w;
            }
        }
        {
            int kk = t >> 4;            // 0..15
            int cg = (t & 15) * 4;
#pragma unroll
            for (int p = 0; p < 2; p++) {
                int kx = kk + p * 16;
                *(float4*)&sB[kx][cg] = *(const float4*)&Bq[(size_t)(k0 + kx) * LL + m0 + cg];
            }
        }
        __syncthreads();
#pragma unroll 8
        for (int kk = 0; kk < BK2; kk++) {
            float4 av = *(const float4*)&sA[kk][tr * 4];
            float4 bv = *(const float4*)&sB[kk][tc * 4];
            float a[4] = {av.x, av.y, av.z, av.w};
            float bv4[4] = {bv.x, bv.y, bv.z, bv.w};
#pragma unroll
            for (int i = 0; i < 4; i++)
#pragma unroll
                for (int j = 0; j < 4; j++) acc[i][j] += a[i] * bv4[j];
        }
        __syncthreads();
    }

    // local packed max per column (enc(value)<<32 | (4095-l): ties -> smallest l)
#pragma unroll
    for (int j = 0; j < 4; j++) {
        unsigned long long best = 0ull;
#pragma unroll
        for (int i = 0; i < 4; i++) {
            unsigned u = __float_as_uint(acc[i][j]);
            u = (u & 0x80000000u) ? ~u : (u | 0x80000000u);
            int l = l0 + tr * 4 + i;
            unsigned long long p = ((unsigned long long)u << 32) | (unsigned)(4095 - l);
            best = (p > best) ? p : best;
        }
        red[tr][tc * 4 + j] = best;
    }
    __syncthreads();
    if (t < 64) {
        unsigned long long best = 0ull;
#pragma unroll
        for (int r = 0; r < 16; r++) {
            unsigned long long p = red[r][t];
            best = (p > best) ? p : best;
        }
        atomicMax(&packed[(size_t)b * LL + m0 + t], best);
    }
}

// ---------------- Kernel 4: decode packed -> S (d_out) + argmax (ws)
__global__ void decode_packed(const unsigned long long* __restrict__ packed,
                              float* __restrict__ S_out, int* __restrict__ arg) {
    int i = blockIdx.x * 256 + threadIdx.x;
    if (i < BB * LL) {
        unsigned long long p = packed[i];
        unsigned u = (unsigned)(p >> 32);
        unsigned bits = (u & 0x80000000u) ? (u & 0x7FFFFFFFu) : ~u;
        S_out[i] = __uint_as_float(bits);
        arg[i] = 4095 - (int)(unsigned)(p & 0xFFFFFFFFull);
    }
}

// ---------------- Kernel 5/7: batched 2D transpose  src[R][Cc] -> dst[Cc][R]
__global__ __launch_bounds__(256) void transpose_mat(const float* __restrict__ src,
                                                     float* __restrict__ dst,
                                                     int R, int Cc) {
    __shared__ float tile[32][33];
    size_t boff = (size_t)blockIdx.z * R * Cc;
    int bx = blockIdx.x;   // col tile
    int by = blockIdx.y;   // row tile
    int tx = threadIdx.x & 31;
    int ty = threadIdx.x >> 5;
    const float* s = src + boff;
    float* d = dst + boff;
#pragma unroll
    for (int i = 0; i < 4; i++) {
        int r = by * 32 + ty + i * 8;
        int c = bx * 32 + tx;
        tile[ty + i * 8][tx] = s[(size_t)r * Cc + c];
    }
    __syncthreads();
#pragma unroll
    for (int i = 0; i < 4; i++) {
        int c = bx * 32 + ty + i * 8;
        int r = by * 32 + tx;
        d[(size_t)c * R + r] = tile[tx][ty + i * 8];
    }
}

// ---------------- Kernel 6: gather + fold (channel-last), one pixel per block
__global__ __launch_bounds__(256) void gather_fold(const float* __restrict__ value_t,
                                                   const int* __restrict__ arg,
                                                   float* __restrict__ T_t) {
    int b = blockIdx.y;
    int pix = blockIdx.x;           // 0..4095
    int y = pix >> 6, x = pix & 63;
    int t = threadIdx.x;            // 2 channels per thread
    float2 acc = make_float2(0.f, 0.f);
    int cnty = (y == 0 || y == HH - 1) ? 2 : 3;
    int cntx = (x == 0 || x == WW - 1) ? 2 : 3;
    const int* ab = arg + b * LL;
    const float* vb = value_t + (size_t)b * LL * CC;
#pragma unroll
    for (int di = 0; di < 3; di++) {
        int my = y + 1 - di;
        if (my < 0 || my >= HH) continue;
#pragma unroll
        for (int dj = 0; dj < 3; dj++) {
            int mx = x + 1 - dj;
            if (mx < 0 || mx >= WW) continue;
            int a = ab[my * WW + mx];
            int ay = a >> 6, ax = a & 63;
            int vy = ay + di - 1, vx = ax + dj - 1;
            if (vy < 0 || vy >= HH || vx < 0 || vx >= WW) continue;
            float2 v = *(const float2*)&vb[((size_t)(vy * WW + vx)) * CC + t * 2];
            acc.x += v.x; acc.y += v.y;
        }
    }
    float inv = 1.0f / (float)(cnty * cntx);
    acc.x *= inv; acc.y *= inv;
    *(float2*)&T_t[((size_t)b * LL + pix) * CC + t * 2] = acc;
}

extern "C" void kernel_launch(void* const* d_in, const int* in_sizes, int n_in,
                              void* d_out, int out_size, void* d_ws, size_t ws_size,
                              hipStream_t stream) {
    const float* query = (const float*)d_in[0];
    const float* key   = (const float*)d_in[1];
    const float* value = (const float*)d_in[2];
    const float* Wemb  = (const float*)d_in[3];
    // d_in[4] = k (always 3)

    float* out   = (float*)d_out;
    float* S_out = out;             // [B][L] = 8192
    float* T_out = out + BB * LL;   // [B][C][L]

    char* ws = (char*)d_ws;
    size_t off = 0;
    float* Wt  = (float*)(ws + off); off += (size_t)CIN * DD * 4;          // 4.72 MB
    float* q_n = (float*)(ws + off); size_t qn_off = off; off += (size_t)BB * DD * LL * 4;  // 8.39 MB
    float* k_n = (float*)(ws + off); off += (size_t)BB * LL * DD * 4;      // 8.39 MB
    float* val_t = (float*)(ws + off); off += (size_t)BB * LL * CC * 4;    // 16.78 MB
    unsigned long long* packed = (unsigned long long*)(ws + off); off += (size_t)BB * LL * 8;
    int* arg = (int*)(ws + off); off += (size_t)BB * LL * 4;
    float* T_t = (float*)(ws + qn_off);  // alias q_n+k_n (dead after corr_max): 16.78 MB

    transposeW   <<<dim3(144, 8), 256, 0, stream>>>(Wemb, Wt);
    embed_norm   <<<dim3(128, 4), 256, 0, stream>>>(query, key, Wt, q_n, k_n);
    init_packed  <<<dim3(32), 256, 0, stream>>>(packed, BB * LL);
    corr_max     <<<dim3(64, 64, 2), 256, 0, stream>>>(k_n, q_n, packed);
    decode_packed<<<dim3(32), 256, 0, stream>>>(packed, S_out, arg);
    transpose_mat<<<dim3(128, 16, 2), 256, 0, stream>>>(value, val_t, CC, LL); // value -> [b][px][c]
    gather_fold  <<<dim3(4096, 2), 256, 0, stream>>>(val_t, arg, T_t);
    transpose_mat<<<dim3(16, 128, 2), 256, 0, stream>>>(T_t, T_out, LL, CC);   // [b][px][c] -> [b][c][px]
}

// Round 2
// 653.910 us; speedup vs baseline: 1.3932x; 1.3932x over previous
//
#include <hip/hip_runtime.h>
#include <hip/hip_bf16.h>
#include <stdint.h>
#include <math.h>

#define BB 2
#define CC 512
#define HH 64
#define WW 64
#define LL 4096
#define DD 256
#define CIN 4608   // 512*9
#define NT 144     // K steps of 32

typedef _Float16 half_t;
typedef __attribute__((ext_vector_type(8))) _Float16 f16x8;
typedef __attribute__((ext_vector_type(4))) _Float16 f16x4;
typedef __attribute__((ext_vector_type(4))) float f32x4;

// ---------------- Kernel 0: split W [256][4608] f32 -> Whi/Wlo f16 (same layout)
__global__ __launch_bounds__(256) void splitW(const float* __restrict__ W,
                                              half_t* __restrict__ Whi,
                                              half_t* __restrict__ Wlo) {
    int i = blockIdx.x * 256 + threadIdx.x;
    if (i < DD * CIN) {
        float w = W[i];
        half_t h = (half_t)w;
        Whi[i] = h;
        Wlo[i] = (half_t)(w - (float)h);
    }
}

// LDS row: 64 halves (32 hi | 32 lo) = 128B, 8 slots of 16B, XOR swizzle by (row&7)
__device__ __forceinline__ half_t* ldsAddr(half_t* base, int r, int slot) {
    return base + r * 64 + ((slot ^ (r & 7)) << 3);
}

// ---------------- Kernel 1: embed via f16 split-3 MFMA + fused D-norm
// C[256 d][64 l] per block; block = one image row y; grid (64, 4 images)
__global__ __launch_bounds__(512) void embed_mfma(const float* __restrict__ query,
                                                  const float* __restrict__ key,
                                                  const half_t* __restrict__ Whi,
                                                  const half_t* __restrict__ Wlo,
                                                  float* __restrict__ q_n,
                                                  float* __restrict__ k_n) {
    __shared__ half_t sB[2][64 * 64];   // 16 KB total
    __shared__ float red[4][64];
    __shared__ float invn[64];

    int iid = blockIdx.y;               // 0..3
    int b = iid & 1, type = iid >> 1;   // 0=query, 1=key
    const float* img = (type ? key : query) + (size_t)b * CC * LL;
    int y = blockIdx.x;                 // image row 0..63
    int t = threadIdx.x;
    int w = t >> 6;                     // wave 0..7
    int lane = t & 63;
    int wr = w >> 1, wc = w & 1;        // wave tile: d base wr*64, l base wc*32
    int fr = lane & 15;                 // fragment row/col
    int fs = lane >> 4;                 // k slot 0..3

    // ---- B staging state: thread stages 4 k-values for pixel x
    int xB = t & 63;
    int kcB = t >> 6;                   // k-chunk (4 k) 0..7
    int k0 = kcB * 4;
    int cS = k0 / 9;
    int offS = k0 - cS * 9;

    f32x4 acc[4][2];
#pragma unroll
    for (int rg = 0; rg < 4; rg++)
#pragma unroll
        for (int cg = 0; cg < 2; cg++) acc[rg][cg] = (f32x4){0.f, 0.f, 0.f, 0.f};

    float Bv[4];

    // load 4 unfold values at current (cS,offS) state, then advance state by 32 k
#define LOADB()                                                          \
    do {                                                                 \
        int cj = cS, oj = offS;                                          \
        _Pragma("unroll")                                                \
        for (int j = 0; j < 4; j++) {                                    \
            int di = oj / 3, dj = oj - di * 3;                           \
            int yy = y + di - 1, xx = xB + dj - 1;                       \
            Bv[j] = (yy >= 0 && yy < HH && xx >= 0 && xx < WW)           \
                        ? img[(size_t)cj * LL + yy * WW + xx] : 0.f;     \
            oj++; if (oj >= 9) { oj = 0; cj++; }                         \
        }                                                                \
        cS += 3; offS += 5; if (offS >= 9) { offS -= 9; cS++; }          \
    } while (0)

#define WRITEB(buf)                                                      \
    do {                                                                 \
        f16x4 h4, l4;                                                    \
        _Pragma("unroll")                                                \
        for (int j = 0; j < 4; j++) {                                    \
            half_t h = (half_t)Bv[j];                                    \
            h4[j] = h; l4[j] = (half_t)(Bv[j] - (float)h);               \
        }                                                                \
        *(f16x4*)(ldsAddr(buf, xB, kcB >> 1) + ((kcB & 1) << 2)) = h4;   \
        *(f16x4*)(ldsAddr(buf, xB, 4 + (kcB >> 1)) + ((kcB & 1) << 2)) = l4; \
    } while (0)

    // prologue: stage tile 0, prefetch tile 1
    LOADB();
    WRITEB(sB[0]);
    LOADB();
    __syncthreads();

    for (int it = 0; it < NT; ++it) {
        half_t* buf = sB[it & 1];
        // B fragments from LDS
        f16x8 bh[2], bl[2];
#pragma unroll
        for (int cg = 0; cg < 2; cg++) {
            int r = wc * 32 + cg * 16 + fr;
            bh[cg] = *(f16x8*)ldsAddr(buf, r, fs);
            bl[cg] = *(f16x8*)ldsAddr(buf, r, fs + 4);
        }
        // A fragments direct from global (L2-resident W, contiguous 16B)
        int kb = it * 32 + fs * 8;
        f16x8 ah[4], al[4];
#pragma unroll
        for (int rg = 0; rg < 4; rg++) {
            size_t off = (size_t)(wr * 64 + rg * 16 + fr) * CIN + kb;
            ah[rg] = *(const f16x8*)(Whi + off);
            al[rg] = *(const f16x8*)(Wlo + off);
        }
        // split-3 MFMA: hi*hi + hi*lo + lo*hi
#pragma unroll
        for (int rg = 0; rg < 4; rg++)
#pragma unroll
            for (int cg = 0; cg < 2; cg++)
                acc[rg][cg] = __builtin_amdgcn_mfma_f32_16x16x32_f16(ah[rg], bh[cg], acc[rg][cg], 0, 0, 0);
#pragma unroll
        for (int rg = 0; rg < 4; rg++)
#pragma unroll
            for (int cg = 0; cg < 2; cg++) {
                acc[rg][cg] = __builtin_amdgcn_mfma_f32_16x16x32_f16(ah[rg], bl[cg], acc[rg][cg], 0, 0, 0);
                acc[rg][cg] = __builtin_amdgcn_mfma_f32_16x16x32_f16(al[rg], bh[cg], acc[rg][cg], 0, 0, 0);
            }

        if (it + 1 < NT) {
            __syncthreads();            // all waves done reading buf[(it+1)&1] (read at it-1)
            WRITEB(sB[(it + 1) & 1]);
            if (it + 2 < NT) LOADB();
        }
        __syncthreads();
    }

    // ---- fused normalization over d (full 256 within block)
    float ss[2] = {0.f, 0.f};
#pragma unroll
    for (int rg = 0; rg < 4; rg++)
#pragma unroll
        for (int cg = 0; cg < 2; cg++)
#pragma unroll
            for (int r = 0; r < 4; r++) ss[cg] += acc[rg][cg][r] * acc[rg][cg][r];
#pragma unroll
    for (int cg = 0; cg < 2; cg++) {
        ss[cg] += __shfl_xor(ss[cg], 16);
        ss[cg] += __shfl_xor(ss[cg], 32);
    }
    if (lane < 16) {
        red[wr][wc * 32 + lane] = ss[0];
        red[wr][wc * 32 + 16 + lane] = ss[1];
    }
    __syncthreads();
    if (t < 64) {
        float s = red[0][t] + red[1][t] + red[2][t] + red[3][t];
        invn[t] = 1.0f / fmaxf(sqrtf(s), 1e-12f);
    }
    __syncthreads();

#pragma unroll
    for (int cg = 0; cg < 2; cg++) {
        int lloc = wc * 32 + cg * 16 + fr;
        float sc = invn[lloc];
        int lg = y * WW + lloc;
#pragma unroll
        for (int rg = 0; rg < 4; rg++) {
#pragma unroll
            for (int r = 0; r < 4; r++) {
                int d = wr * 64 + rg * 16 + fs * 4 + r;
                float v = acc[rg][cg][r] * sc;
                if (type == 0) q_n[((size_t)b * DD + d) * LL + lg] = v;
                else           k_n[((size_t)b * LL + lg) * DD + d] = v;
            }
        }
    }
#undef LOADB
#undef WRITEB
}

// ---------------- Kernel 2: init packed max buffer
__global__ void init_packed(unsigned long long* p, int n) {
    int i = blockIdx.x * 256 + threadIdx.x;
    if (i < n) p[i] = 0ull;
}

// ---------------- Kernel 3: corr GEMM + fused column max/argmax (fp32, verified)
#define BM2 64
#define BN2 64
#define BK2 32
__global__ __launch_bounds__(256) void corr_max(const float* __restrict__ k_n,
                                                const float* __restrict__ q_n,
                                                unsigned long long* __restrict__ packed) {
    __shared__ float sA[BK2][68];
    __shared__ float sB[BK2][BN2];
    __shared__ unsigned long long red[16][64];

    int b  = blockIdx.z;
    int l0 = blockIdx.y * BM2;
    int m0 = blockIdx.x * BN2;
    int t  = threadIdx.x;
    int tr = t >> 4, tc = t & 15;

    const float* A  = k_n + (size_t)b * LL * DD;
    const float* Bq = q_n + (size_t)b * DD * LL;

    float acc[4][4];
#pragma unroll
    for (int i = 0; i < 4; i++)
#pragma unroll
        for (int j = 0; j < 4; j++) acc[i][j] = 0.f;

    for (int k0 = 0; k0 < DD; k0 += BK2) {
        {
            int r  = t >> 3;
            int kg = (t & 7) * 4;
#pragma unroll
            for (int p = 0; p < 2; p++) {
                int rr = r + p * 32;
                float4 v = *(const float4*)&A[(size_t)(l0 + rr) * DD + k0 + kg];
                sA[kg + 0][rr] = v.x; sA[kg + 1][rr] = v.y;
                sA[kg + 2][rr] = v.z; sA[kg + 3][rr] = v.w;
            }
        }
        {
            int kk = t >> 4;
            int cg = (t & 15) * 4;
#pragma unroll
            for (int p = 0; p < 2; p++) {
                int kx = kk + p * 16;
                *(float4*)&sB[kx][cg] = *(const float4*)&Bq[(size_t)(k0 + kx) * LL + m0 + cg];
            }
        }
        __syncthreads();
#pragma unroll 8
        for (int kk = 0; kk < BK2; kk++) {
            float4 av = *(const float4*)&sA[kk][tr * 4];
            float4 bv = *(const float4*)&sB[kk][tc * 4];
            float a[4] = {av.x, av.y, av.z, av.w};
            float bv4[4] = {bv.x, bv.y, bv.z, bv.w};
#pragma unroll
            for (int i = 0; i < 4; i++)
#pragma unroll
                for (int j = 0; j < 4; j++) acc[i][j] += a[i] * bv4[j];
        }
        __syncthreads();
    }

#pragma unroll
    for (int j = 0; j < 4; j++) {
        unsigned long long best = 0ull;
#pragma unroll
        for (int i = 0; i < 4; i++) {
            unsigned u = __float_as_uint(acc[i][j]);
            u = (u & 0x80000000u) ? ~u : (u | 0x80000000u);
            int l = l0 + tr * 4 + i;
            unsigned long long p = ((unsigned long long)u << 32) | (unsigned)(4095 - l);
            best = (p > best) ? p : best;
        }
        red[tr][tc * 4 + j] = best;
    }
    __syncthreads();
    if (t < 64) {
        unsigned long long best = 0ull;
#pragma unroll
        for (int r = 0; r < 16; r++) {
            unsigned long long p = red[r][t];
            best = (p > best) ? p : best;
        }
        atomicMax(&packed[(size_t)b * LL + m0 + t], best);
    }
}

// ---------------- Kernel 4: decode packed -> S (d_out) + argmax (ws)
__global__ void decode_packed(const unsigned long long* __restrict__ packed,
                              float* __restrict__ S_out, int* __restrict__ arg) {
    int i = blockIdx.x * 256 + threadIdx.x;
    if (i < BB * LL) {
        unsigned long long p = packed[i];
        unsigned u = (unsigned)(p >> 32);
        unsigned bits = (u & 0x80000000u) ? (u & 0x7FFFFFFFu) : ~u;
        S_out[i] = __uint_as_float(bits);
        arg[i] = 4095 - (int)(unsigned)(p & 0xFFFFFFFFull);
    }
}

// ---------------- Kernel 5/7: batched 2D transpose src[R][Cc] -> dst[Cc][R]
__global__ __launch_bounds__(256) void transpose_mat(const float* __restrict__ src,
                                                     float* __restrict__ dst,
                                                     int R, int Cc) {
    __shared__ float tile[32][33];
    size_t boff = (size_t)blockIdx.z * R * Cc;
    int bx = blockIdx.x;
    int by = blockIdx.y;
    int tx = threadIdx.x & 31;
    int ty = threadIdx.x >> 5;
    const float* s = src + boff;
    float* d = dst + boff;
#pragma unroll
    for (int i = 0; i < 4; i++) {
        int r = by * 32 + ty + i * 8;
        int c = bx * 32 + tx;
        tile[ty + i * 8][tx] = s[(size_t)r * Cc + c];
    }
    __syncthreads();
#pragma unroll
    for (int i = 0; i < 4; i++) {
        int c = bx * 32 + ty + i * 8;
        int r = by * 32 + tx;
        d[(size_t)c * R + r] = tile[tx][ty + i * 8];
    }
}

// ---------------- Kernel 6: gather + fold (channel-last), one pixel per block
__global__ __launch_bounds__(256) void gather_fold(const float* __restrict__ value_t,
                                                   const int* __restrict__ arg,
                                                   float* __restrict__ T_t) {
    int b = blockIdx.y;
    int pix = blockIdx.x;
    int y = pix >> 6, x = pix & 63;
    int t = threadIdx.x;
    float2 acc = make_float2(0.f, 0.f);
    int cnty = (y == 0 || y == HH - 1) ? 2 : 3;
    int cntx = (x == 0 || x == WW - 1) ? 2 : 3;
    const int* ab = arg + b * LL;
    const float* vb = value_t + (size_t)b * LL * CC;
#pragma unroll
    for (int di = 0; di < 3; di++) {
        int my = y + 1 - di;
        if (my < 0 || my >= HH) continue;
#pragma unroll
        for (int dj = 0; dj < 3; dj++) {
            int mx = x + 1 - dj;
            if (mx < 0 || mx >= WW) continue;
            int a = ab[my * WW + mx];
            int ay = a >> 6, ax = a & 63;
            int vy = ay + di - 1, vx = ax + dj - 1;
            if (vy < 0 || vy >= HH || vx < 0 || vx >= WW) continue;
            float2 v = *(const float2*)&vb[((size_t)(vy * WW + vx)) * CC + t * 2];
            acc.x += v.x; acc.y += v.y;
        }
    }
    float inv = 1.0f / (float)(cnty * cntx);
    acc.x *= inv; acc.y *= inv;
    *(float2*)&T_t[((size_t)b * LL + pix) * CC + t * 2] = acc;
}

extern "C" void kernel_launch(void* const* d_in, const int* in_sizes, int n_in,
                              void* d_out, int out_size, void* d_ws, size_t ws_size,
                              hipStream_t stream) {
    const float* query = (const float*)d_in[0];
    const float* key   = (const float*)d_in[1];
    const float* value = (const float*)d_in[2];
    const float* Wemb  = (const float*)d_in[3];

    float* out   = (float*)d_out;
    float* S_out = out;
    float* T_out = out + BB * LL;

    char* ws = (char*)d_ws;
    size_t off = 0;
    half_t* Whi = (half_t*)(ws + off); off += (size_t)DD * CIN * 2;        // 2.36 MB
    half_t* Wlo = (half_t*)(ws + off); off += (size_t)DD * CIN * 2;        // 2.36 MB
    float* q_n = (float*)(ws + off); size_t qn_off = off; off += (size_t)BB * DD * LL * 4;
    float* k_n = (float*)(ws + off); off += (size_t)BB * LL * DD * 4;
    float* val_t = (float*)(ws + off); off += (size_t)BB * LL * CC * 4;
    unsigned long long* packed = (unsigned long long*)(ws + off); off += (size_t)BB * LL * 8;
    int* arg = (int*)(ws + off); off += (size_t)BB * LL * 4;
    float* T_t = (float*)(ws + qn_off);  // alias q_n+k_n (dead after corr_max)

    splitW       <<<dim3((DD * CIN + 255) / 256), 256, 0, stream>>>(Wemb, Whi, Wlo);
    embed_mfma   <<<dim3(64, 4), 512, 0, stream>>>(query, key, Whi, Wlo, q_n, k_n);
    init_packed  <<<dim3(32), 256, 0, stream>>>(packed, BB * LL);
    corr_max     <<<dim3(64, 64, 2), 256, 0, stream>>>(k_n, q_n, packed);
    decode_packed<<<dim3(32), 256, 0, stream>>>(packed, S_out, arg);
    transpose_mat<<<dim3(128, 16, 2), 256, 0, stream>>>(value, val_t, CC, LL);
    gather_fold  <<<dim3(4096, 2), 256, 0, stream>>>(val_t, arg, T_t);
    transpose_mat<<<dim3(16, 128, 2), 256, 0, stream>>>(T_t, T_out, LL, CC);
}

// Round 3
// 588.824 us; speedup vs baseline: 1.5472x; 1.1105x over previous
//
#include <hip/hip_runtime.h>
#include <hip/hip_bf16.h>
#include <stdint.h>
#include <math.h>

#define BB 2
#define CC 512
#define HH 64
#define WW 64
#define LL 4096
#define DD 256
#define CIN 4608   // 512*9
#define NT 144     // K steps of 32

typedef _Float16 half_t;
typedef __attribute__((ext_vector_type(8))) _Float16 f16x8;
typedef __attribute__((ext_vector_type(4))) _Float16 f16x4;
typedef __attribute__((ext_vector_type(4))) float f32x4;

// ---------------- Kernel 0: split W [256][4608] f32 -> Whi/Wlo f16 (same layout)
__global__ __launch_bounds__(256) void splitW(const float* __restrict__ W,
                                              half_t* __restrict__ Whi,
                                              half_t* __restrict__ Wlo) {
    int i = blockIdx.x * 256 + threadIdx.x;
    if (i < DD * CIN) {
        float w = W[i];
        half_t h = (half_t)w;
        Whi[i] = h;
        Wlo[i] = (half_t)(w - (float)h);
    }
}

// LDS row: 64 halves (32 hi | 32 lo) = 128B, 8 slots of 16B, XOR swizzle by (row&7)
__device__ __forceinline__ half_t* ldsAddr(half_t* base, int r, int slot) {
    return base + r * 64 + ((slot ^ (r & 7)) << 3);
}

// ---------------- Kernel 1: embed via f16 split-3 MFMA + fused D-norm
// C[256 d][64 l] per block; block = one image row y; grid (64, 4 images)
// Output: normalized embeddings as hi/lo f16 pairs, layout [b][L][D]
__global__ __launch_bounds__(512) void embed_mfma(const float* __restrict__ query,
                                                  const float* __restrict__ key,
                                                  const half_t* __restrict__ Whi,
                                                  const half_t* __restrict__ Wlo,
                                                  half_t* __restrict__ qhi,
                                                  half_t* __restrict__ qlo,
                                                  half_t* __restrict__ khi,
                                                  half_t* __restrict__ klo) {
    __shared__ half_t sB[2][64 * 64];   // 16 KB total
    __shared__ float red[4][64];
    __shared__ float invn[64];

    int iid = blockIdx.y;               // 0..3
    int b = iid & 1, type = iid >> 1;   // 0=query, 1=key
    const float* img = (type ? key : query) + (size_t)b * CC * LL;
    int y = blockIdx.x;                 // image row 0..63
    int t = threadIdx.x;
    int w = t >> 6;                     // wave 0..7
    int lane = t & 63;
    int wr = w >> 1, wc = w & 1;        // wave tile: d base wr*64, l base wc*32
    int fr = lane & 15;                 // fragment row/col
    int fs = lane >> 4;                 // k slot 0..3

    // ---- B staging state: thread stages 4 k-values for pixel x
    int xB = t & 63;
    int kcB = t >> 6;                   // k-chunk (4 k) 0..7
    int k0 = kcB * 4;
    int cS = k0 / 9;
    int offS = k0 - cS * 9;

    f32x4 acc[4][2];
#pragma unroll
    for (int rg = 0; rg < 4; rg++)
#pragma unroll
        for (int cg = 0; cg < 2; cg++) acc[rg][cg] = (f32x4){0.f, 0.f, 0.f, 0.f};

    float Bv[4];

    // load 4 unfold values at current (cS,offS) state, then advance state by 32 k
#define LOADB()                                                          \
    do {                                                                 \
        int cj = cS, oj = offS;                                          \
        _Pragma("unroll")                                                \
        for (int j = 0; j < 4; j++) {                                    \
            int di = oj / 3, dj = oj - di * 3;                           \
            int yy = y + di - 1, xx = xB + dj - 1;                       \
            Bv[j] = (yy >= 0 && yy < HH && xx >= 0 && xx < WW)           \
                        ? img[(size_t)cj * LL + yy * WW + xx] : 0.f;     \
            oj++; if (oj >= 9) { oj = 0; cj++; }                         \
        }                                                                \
        cS += 3; offS += 5; if (offS >= 9) { offS -= 9; cS++; }          \
    } while (0)

#define WRITEB(buf)                                                      \
    do {                                                                 \
        f16x4 h4, l4;                                                    \
        _Pragma("unroll")                                                \
        for (int j = 0; j < 4; j++) {                                    \
            half_t h = (half_t)Bv[j];                                    \
            h4[j] = h; l4[j] = (half_t)(Bv[j] - (float)h);               \
        }                                                                \
        *(f16x4*)(ldsAddr(buf, xB, kcB >> 1) + ((kcB & 1) << 2)) = h4;   \
        *(f16x4*)(ldsAddr(buf, xB, 4 + (kcB >> 1)) + ((kcB & 1) << 2)) = l4; \
    } while (0)

    // prologue: stage tile 0, prefetch tile 1 into regs
    LOADB();
    WRITEB(sB[0]);
    LOADB();
    __syncthreads();

    // steady state (ONE barrier per iteration):
    //   tile it ready in buf[it&1]; tile it+1 in regs; issue tile it+2 loads
    for (int it = 0; it < NT; ++it) {
        half_t* buf = sB[it & 1];
        // B fragments from LDS (tile it)
        f16x8 bh[2], bl[2];
#pragma unroll
        for (int cg = 0; cg < 2; cg++) {
            int r = wc * 32 + cg * 16 + fr;
            bh[cg] = *(f16x8*)ldsAddr(buf, r, fs);
            bl[cg] = *(f16x8*)ldsAddr(buf, r, fs + 4);
        }
        // tile it+1: regs -> other buffer (prev barrier fenced all reads of it)
        if (it + 1 < NT) WRITEB(sB[(it + 1) & 1]);
        // tile it+2: issue global loads; land during MFMA below
        if (it + 2 < NT) LOADB();
        // A fragments direct from global (L2-resident W, contiguous 16B)
        int kb = it * 32 + fs * 8;
        f16x8 ah[4], al[4];
#pragma unroll
        for (int rg = 0; rg < 4; rg++) {
            size_t woff = (size_t)(wr * 64 + rg * 16 + fr) * CIN + kb;
            ah[rg] = *(const f16x8*)(Whi + woff);
            al[rg] = *(const f16x8*)(Wlo + woff);
        }
        // split-3 MFMA: hi*hi + hi*lo + lo*hi
#pragma unroll
        for (int rg = 0; rg < 4; rg++)
#pragma unroll
            for (int cg = 0; cg < 2; cg++)
                acc[rg][cg] = __builtin_amdgcn_mfma_f32_16x16x32_f16(ah[rg], bh[cg], acc[rg][cg], 0, 0, 0);
#pragma unroll
        for (int rg = 0; rg < 4; rg++)
#pragma unroll
            for (int cg = 0; cg < 2; cg++) {
                acc[rg][cg] = __builtin_amdgcn_mfma_f32_16x16x32_f16(ah[rg], bl[cg], acc[rg][cg], 0, 0, 0);
                acc[rg][cg] = __builtin_amdgcn_mfma_f32_16x16x32_f16(al[rg], bh[cg], acc[rg][cg], 0, 0, 0);
            }
        __syncthreads();
    }

    // ---- fused normalization over d (full 256 within block)
    float ss[2] = {0.f, 0.f};
#pragma unroll
    for (int rg = 0; rg < 4; rg++)
#pragma unroll
        for (int cg = 0; cg < 2; cg++)
#pragma unroll
            for (int r = 0; r < 4; r++) ss[cg] += acc[rg][cg][r] * acc[rg][cg][r];
#pragma unroll
    for (int cg = 0; cg < 2; cg++) {
        ss[cg] += __shfl_xor(ss[cg], 16);
        ss[cg] += __shfl_xor(ss[cg], 32);
    }
    if (lane < 16) {
        red[wr][wc * 32 + lane] = ss[0];
        red[wr][wc * 32 + 16 + lane] = ss[1];
    }
    __syncthreads();
    if (t < 64) {
        float s = red[0][t] + red[1][t] + red[2][t] + red[3][t];
        invn[t] = 1.0f / fmaxf(sqrtf(s), 1e-12f);
    }
    __syncthreads();

    half_t* ehi = (type == 0) ? qhi : khi;
    half_t* elo = (type == 0) ? qlo : klo;
#pragma unroll
    for (int cg = 0; cg < 2; cg++) {
        int lloc = wc * 32 + cg * 16 + fr;
        float sc = invn[lloc];
        size_t lrow = ((size_t)b * LL + y * WW + lloc) * DD;
#pragma unroll
        for (int rg = 0; rg < 4; rg++) {
            int d0 = wr * 64 + rg * 16 + fs * 4;
            f16x4 h4, l4;
#pragma unroll
            for (int r = 0; r < 4; r++) {
                float v = acc[rg][cg][r] * sc;
                half_t h = (half_t)v;
                h4[r] = h;
                l4[r] = (half_t)(v - (float)h);
            }
            *(f16x4*)&ehi[lrow + d0] = h4;
            *(f16x4*)&elo[lrow + d0] = l4;
        }
    }
#undef LOADB
#undef WRITEB
}

// ---------------- Kernel 2: init packed max buffer
__global__ void init_packed(unsigned long long* p, int n) {
    int i = blockIdx.x * 256 + threadIdx.x;
    if (i < n) p[i] = 0ull;
}

// ---------------- Kernel 3: corr via split-3 f16 MFMA + fused column max/argmax
// corr[l,m] = k_n[l,:] . q_n[m,:]  (both [L][D] row-major) ; max/argmax over l per m
__global__ __launch_bounds__(256) void corr_max_mfma(const half_t* __restrict__ khi,
                                                     const half_t* __restrict__ klo,
                                                     const half_t* __restrict__ qhi,
                                                     const half_t* __restrict__ qlo,
                                                     unsigned long long* __restrict__ packed) {
    int b = blockIdx.z;
    int l0 = blockIdx.y * 64;
    int m0 = blockIdx.x * 64;
    int t = threadIdx.x;
    int w = t >> 6, lane = t & 63;
    int wr = w >> 1, wc = w & 1;        // wave tile: l base wr*32, m base wc*32
    int fr = lane & 15, fs = lane >> 4;

    const half_t* Ah = khi + (size_t)b * LL * DD;
    const half_t* Al = klo + (size_t)b * LL * DD;
    const half_t* Bh = qhi + (size_t)b * LL * DD;
    const half_t* Bl = qlo + (size_t)b * LL * DD;

    f32x4 acc[2][2];
#pragma unroll
    for (int i = 0; i < 2; i++)
#pragma unroll
        for (int j = 0; j < 2; j++) acc[i][j] = (f32x4){0.f, 0.f, 0.f, 0.f};

    for (int k0 = 0; k0 < DD; k0 += 32) {
        f16x8 a_h[2], a_l[2], b_h[2], b_l[2];
#pragma unroll
        for (int rg = 0; rg < 2; rg++) {
            size_t roff = (size_t)(l0 + wr * 32 + rg * 16 + fr) * DD + k0 + fs * 8;
            a_h[rg] = *(const f16x8*)(Ah + roff);
            a_l[rg] = *(const f16x8*)(Al + roff);
        }
#pragma unroll
        for (int cg = 0; cg < 2; cg++) {
            size_t coff = (size_t)(m0 + wc * 32 + cg * 16 + fr) * DD + k0 + fs * 8;
            b_h[cg] = *(const f16x8*)(Bh + coff);
            b_l[cg] = *(const f16x8*)(Bl + coff);
        }
#pragma unroll
        for (int rg = 0; rg < 2; rg++)
#pragma unroll
            for (int cg = 0; cg < 2; cg++) {
                acc[rg][cg] = __builtin_amdgcn_mfma_f32_16x16x32_f16(a_h[rg], b_h[cg], acc[rg][cg], 0, 0, 0);
                acc[rg][cg] = __builtin_amdgcn_mfma_f32_16x16x32_f16(a_h[rg], b_l[cg], acc[rg][cg], 0, 0, 0);
                acc[rg][cg] = __builtin_amdgcn_mfma_f32_16x16x32_f16(a_l[rg], b_h[cg], acc[rg][cg], 0, 0, 0);
            }
    }

    // C layout: col(m) = lane&15, row(l) = fs*4 + r within fragment
#pragma unroll
    for (int cg = 0; cg < 2; cg++) {
        unsigned long long best = 0ull;
#pragma unroll
        for (int rg = 0; rg < 2; rg++) {
#pragma unroll
            for (int r = 0; r < 4; r++) {
                unsigned u = __float_as_uint(acc[rg][cg][r]);
                u = (u & 0x80000000u) ? ~u : (u | 0x80000000u);
                int l = l0 + wr * 32 + rg * 16 + fs * 4 + r;
                unsigned long long p = ((unsigned long long)u << 32) | (unsigned)(4095 - l);
                best = (p > best) ? p : best;
            }
        }
        unsigned long long o;
        o = __shfl_xor(best, 16); best = (o > best) ? o : best;
        o = __shfl_xor(best, 32); best = (o > best) ? o : best;
        if (lane < 16)
            atomicMax(&packed[(size_t)b * LL + m0 + wc * 32 + cg * 16 + lane], best);
    }
}

// ---------------- Kernel 4: decode packed -> S (d_out) + argmax (ws)
__global__ void decode_packed(const unsigned long long* __restrict__ packed,
                              float* __restrict__ S_out, int* __restrict__ arg) {
    int i = blockIdx.x * 256 + threadIdx.x;
    if (i < BB * LL) {
        unsigned long long p = packed[i];
        unsigned u = (unsigned)(p >> 32);
        unsigned bits = (u & 0x80000000u) ? (u & 0x7FFFFFFFu) : ~u;
        S_out[i] = __uint_as_float(bits);
        arg[i] = 4095 - (int)(unsigned)(p & 0xFFFFFFFFull);
    }
}

// ---------------- Kernel 5/7: batched 2D transpose src[R][Cc] -> dst[Cc][R]
__global__ __launch_bounds__(256) void transpose_mat(const float* __restrict__ src,
                                                     float* __restrict__ dst,
                                                     int R, int Cc) {
    __shared__ float tile[32][33];
    size_t boff = (size_t)blockIdx.z * R * Cc;
    int bx = blockIdx.x;
    int by = blockIdx.y;
    int tx = threadIdx.x & 31;
    int ty = threadIdx.x >> 5;
    const float* s = src + boff;
    float* d = dst + boff;
#pragma unroll
    for (int i = 0; i < 4; i++) {
        int r = by * 32 + ty + i * 8;
        int c = bx * 32 + tx;
        tile[ty + i * 8][tx] = s[(size_t)r * Cc + c];
    }
    __syncthreads();
#pragma unroll
    for (int i = 0; i < 4; i++) {
        int c = bx * 32 + ty + i * 8;
        int r = by * 32 + tx;
        d[(size_t)c * R + r] = tile[tx][ty + i * 8];
    }
}

// ---------------- Kernel 6: gather + fold (channel-last), one pixel per block
__global__ __launch_bounds__(256) void gather_fold(const float* __restrict__ value_t,
                                                   const int* __restrict__ arg,
                                                   float* __restrict__ T_t) {
    int b = blockIdx.y;
    int pix = blockIdx.x;
    int y = pix >> 6, x = pix & 63;
    int t = threadIdx.x;
    float2 acc = make_float2(0.f, 0.f);
    int cnty = (y == 0 || y == HH - 1) ? 2 : 3;
    int cntx = (x == 0 || x == WW - 1) ? 2 : 3;
    const int* ab = arg + b * LL;
    const float* vb = value_t + (size_t)b * LL * CC;
#pragma unroll
    for (int di = 0; di < 3; di++) {
        int my = y + 1 - di;
        if (my < 0 || my >= HH) continue;
#pragma unroll
        for (int dj = 0; dj < 3; dj++) {
            int mx = x + 1 - dj;
            if (mx < 0 || mx >= WW) continue;
            int a = ab[my * WW + mx];
            int ay = a >> 6, ax = a & 63;
            int vy = ay + di - 1, vx = ax + dj - 1;
            if (vy < 0 || vy >= HH || vx < 0 || vx >= WW) continue;
            float2 v = *(const float2*)&vb[((size_t)(vy * WW + vx)) * CC + t * 2];
            acc.x += v.x; acc.y += v.y;
        }
    }
    float inv = 1.0f / (float)(cnty * cntx);
    acc.x *= inv; acc.y *= inv;
    *(float2*)&T_t[((size_t)b * LL + pix) * CC + t * 2] = acc;
}

extern "C" void kernel_launch(void* const* d_in, const int* in_sizes, int n_in,
                              void* d_out, int out_size, void* d_ws, size_t ws_size,
                              hipStream_t stream) {
    const float* query = (const float*)d_in[0];
    const float* key   = (const float*)d_in[1];
    const float* value = (const float*)d_in[2];
    const float* Wemb  = (const float*)d_in[3];

    float* out   = (float*)d_out;
    float* S_out = out;
    float* T_out = out + BB * LL;

    char* ws = (char*)d_ws;
    size_t off = 0;
    half_t* Whi = (half_t*)(ws + off); off += (size_t)DD * CIN * 2;        // 2.36 MB
    half_t* Wlo = (half_t*)(ws + off); off += (size_t)DD * CIN * 2;        // 2.36 MB
    half_t* qhi = (half_t*)(ws + off); size_t emb_off = off; off += (size_t)BB * LL * DD * 2;  // 4.19 MB
    half_t* qlo = (half_t*)(ws + off); off += (size_t)BB * LL * DD * 2;
    half_t* khi = (half_t*)(ws + off); off += (size_t)BB * LL * DD * 2;
    half_t* klo = (half_t*)(ws + off); off += (size_t)BB * LL * DD * 2;
    float* val_t = (float*)(ws + off); off += (size_t)BB * LL * CC * 4;    // 16.78 MB
    unsigned long long* packed = (unsigned long long*)(ws + off); off += (size_t)BB * LL * 8;
    int* arg = (int*)(ws + off); off += (size_t)BB * LL * 4;
    float* T_t = (float*)(ws + emb_off);  // alias embed splits (dead after corr): 16.78 MB

    splitW        <<<dim3((DD * CIN + 255) / 256), 256, 0, stream>>>(Wemb, Whi, Wlo);
    embed_mfma    <<<dim3(64, 4), 512, 0, stream>>>(query, key, Whi, Wlo, qhi, qlo, khi, klo);
    init_packed   <<<dim3(32), 256, 0, stream>>>(packed, BB * LL);
    corr_max_mfma <<<dim3(64, 64, 2), 256, 0, stream>>>(khi, klo, qhi, qlo, packed);
    decode_packed <<<dim3(32), 256, 0, stream>>>(packed, S_out, arg);
    transpose_mat <<<dim3(128, 16, 2), 256, 0, stream>>>(value, val_t, CC, LL);
    gather_fold   <<<dim3(4096, 2), 256, 0, stream>>>(val_t, arg, T_t);
    transpose_mat <<<dim3(16, 128, 2), 256, 0, stream>>>(T_t, T_out, LL, CC);
}

// Round 4
// 556.649 us; speedup vs baseline: 1.6367x; 1.0578x over previous
//
#include <hip/hip_runtime.h>
#include <hip/hip_bf16.h>
#include <stdint.h>
#include <math.h>

#define BB 2
#define CC 512
#define HH 64
#define WW 64
#define LL 4096
#define DD 256
#define CIN 4608   // 512*9
#define NT 144     // K steps of 32

typedef _Float16 half_t;
typedef __attribute__((ext_vector_type(8))) _Float16 f16x8;
typedef __attribute__((ext_vector_type(4))) _Float16 f16x4;
typedef __attribute__((ext_vector_type(4))) float f32x4;

// ---------------- Kernel 0: split W [256][4608] f32 -> Whi/Wlo f16 (same layout)
__global__ __launch_bounds__(256) void splitW(const float* __restrict__ W,
                                              half_t* __restrict__ Whi,
                                              half_t* __restrict__ Wlo) {
    int i = blockIdx.x * 256 + threadIdx.x;
    if (i < DD * CIN) {
        float w = W[i];
        half_t h = (half_t)w;
        Whi[i] = h;
        Wlo[i] = (half_t)(w - (float)h);
    }
}

// LDS row: 64 halves (32 hi | 32 lo) = 128B, 8 slots of 16B, XOR swizzle by (row&7)
__device__ __forceinline__ half_t* ldsAddr(half_t* base, int r, int slot) {
    return base + r * 64 + ((slot ^ (r & 7)) << 3);
}

// non-draining barrier: drain LDS ops (visibility), keep VMEM loads in flight
#define BAR() do { asm volatile("s_waitcnt lgkmcnt(0)" ::: "memory"); \
                   __builtin_amdgcn_s_barrier(); } while (0)

// ---------------- Kernel 1: embed via f16 split-3 MFMA + fused D-norm
// C[256 d][32 l] per block; 4 waves (wave = 64d x 32l); grid (128 ltiles, 4 images)
// = 512 blocks -> 2 blocks/CU. Output: normalized hi/lo f16 pairs, layout [b][L][D]
__global__ __launch_bounds__(256, 2) void embed_mfma(const float* __restrict__ query,
                                                     const float* __restrict__ key,
                                                     const half_t* __restrict__ Whi,
                                                     const half_t* __restrict__ Wlo,
                                                     half_t* __restrict__ qhi,
                                                     half_t* __restrict__ qlo,
                                                     half_t* __restrict__ khi,
                                                     half_t* __restrict__ klo) {
    __shared__ half_t sB[2][32 * 64];   // 8 KB total
    __shared__ float red[4][32];
    __shared__ float invn[32];

    int iid = blockIdx.y;               // 0..3
    int b = iid & 1, type = iid >> 1;   // 0=query, 1=key
    const float* img = (type ? key : query) + (size_t)b * CC * LL;
    int l0 = blockIdx.x * 32;           // 0..4064
    int y  = l0 >> 6;                   // image row
    int x0 = l0 & 63;                   // 0 or 32
    int t = threadIdx.x;
    int w = t >> 6;                     // wave 0..3
    int lane = t & 63;
    int wr = w;                         // wave d base wr*64
    int fr = lane & 15;                 // fragment row/col
    int fs = lane >> 4;                 // k slot 0..3

    // ---- B staging state: thread stages 4 k-values for pixel x0+xB
    int xB = t & 31;
    int kcB = t >> 5;                   // k-chunk (4 k) 0..7
    int k0 = kcB * 4;
    int cS = k0 / 9;
    int offS = k0 - cS * 9;

    f32x4 acc[4][2];
#pragma unroll
    for (int rg = 0; rg < 4; rg++)
#pragma unroll
        for (int cg = 0; cg < 2; cg++) acc[rg][cg] = (f32x4){0.f, 0.f, 0.f, 0.f};

    float Bv[4];

#define LOADB()                                                          \
    do {                                                                 \
        int cj = cS, oj = offS;                                          \
        _Pragma("unroll")                                                \
        for (int j = 0; j < 4; j++) {                                    \
            int di = oj / 3, dj = oj - di * 3;                           \
            int yy = y + di - 1, xx = x0 + xB + dj - 1;                  \
            Bv[j] = (yy >= 0 && yy < HH && xx >= 0 && xx < WW)           \
                        ? img[(size_t)cj * LL + yy * WW + xx] : 0.f;     \
            oj++; if (oj >= 9) { oj = 0; cj++; }                         \
        }                                                                \
        cS += 3; offS += 5; if (offS >= 9) { offS -= 9; cS++; }          \
    } while (0)

#define WRITEB(buf)                                                      \
    do {                                                                 \
        f16x4 h4, l4;                                                    \
        _Pragma("unroll")                                                \
        for (int j = 0; j < 4; j++) {                                    \
            half_t h = (half_t)Bv[j];                                    \
            h4[j] = h; l4[j] = (half_t)(Bv[j] - (float)h);               \
        }                                                                \
        *(f16x4*)(ldsAddr(buf, xB, kcB >> 1) + ((kcB & 1) << 2)) = h4;   \
        *(f16x4*)(ldsAddr(buf, xB, 4 + (kcB >> 1)) + ((kcB & 1) << 2)) = l4; \
    } while (0)

#define LOADA(AH, AL, itv)                                               \
    do {                                                                 \
        int kb = (itv) * 32 + fs * 8;                                    \
        _Pragma("unroll")                                                \
        for (int rg = 0; rg < 4; rg++) {                                 \
            size_t woff = (size_t)(wr * 64 + rg * 16 + fr) * CIN + kb;   \
            AH[rg] = *(const f16x8*)(Whi + woff);                        \
            AL[rg] = *(const f16x8*)(Wlo + woff);                        \
        }                                                                \
    } while (0)

#define READB(buf)                                                       \
    do {                                                                 \
        _Pragma("unroll")                                                \
        for (int cg = 0; cg < 2; cg++) {                                 \
            int r = cg * 16 + fr;                                        \
            bh[cg] = *(f16x8*)ldsAddr(buf, r, fs);                       \
            bl[cg] = *(f16x8*)ldsAddr(buf, r, fs + 4);                   \
        }                                                                \
    } while (0)

#define DOMFMA(AH, AL)                                                   \
    do {                                                                 \
        _Pragma("unroll")                                                \
        for (int rg = 0; rg < 4; rg++)                                   \
            _Pragma("unroll")                                            \
            for (int cg = 0; cg < 2; cg++)                               \
                acc[rg][cg] = __builtin_amdgcn_mfma_f32_16x16x32_f16(AH[rg], bh[cg], acc[rg][cg], 0, 0, 0); \
        _Pragma("unroll")                                                \
        for (int rg = 0; rg < 4; rg++)                                   \
            _Pragma("unroll")                                            \
            for (int cg = 0; cg < 2; cg++) {                             \
                acc[rg][cg] = __builtin_amdgcn_mfma_f32_16x16x32_f16(AH[rg], bl[cg], acc[rg][cg], 0, 0, 0); \
                acc[rg][cg] = __builtin_amdgcn_mfma_f32_16x16x32_f16(AL[rg], bh[cg], acc[rg][cg], 0, 0, 0); \
            }                                                            \
    } while (0)

    f16x8 aAh[4], aAl[4], aBh[4], aBl[4];
    f16x8 bh[2], bl[2];

    // prologue: stage tile 0; regs hold tile 1; A frags for step 0
    LOADB();
    WRITEB(sB[0]);
    LOADB();
    LOADA(aAh, aAl, 0);
    BAR();

    for (int it2 = 0; it2 < NT; it2 += 2) {
        // ---- even step: it = it2, buf sB[0], A = aA
        READB(sB[0]);
        WRITEB(sB[1]);                          // tile it2+1
        if (it2 + 2 < NT) LOADB();              // stage data for tile it2+2
        LOADA(aBh, aBl, it2 + 1);               // A frags for next step
        DOMFMA(aAh, aAl);
        BAR();
        // ---- odd step: it = it2+1, buf sB[1], A = aB
        READB(sB[1]);
        if (it2 + 2 < NT) {
            WRITEB(sB[0]);                      // tile it2+2
            if (it2 + 3 < NT) LOADB();          // stage data for tile it2+3
            LOADA(aAh, aAl, it2 + 2);
        }
        DOMFMA(aBh, aBl);
        BAR();
    }

    // ---- fused normalization over d (full 256 within block)
    float ss[2] = {0.f, 0.f};
#pragma unroll
    for (int rg = 0; rg < 4; rg++)
#pragma unroll
        for (int cg = 0; cg < 2; cg++)
#pragma unroll
            for (int r = 0; r < 4; r++) ss[cg] += acc[rg][cg][r] * acc[rg][cg][r];
#pragma unroll
    for (int cg = 0; cg < 2; cg++) {
        ss[cg] += __shfl_xor(ss[cg], 16);
        ss[cg] += __shfl_xor(ss[cg], 32);
    }
    if (lane < 16) { red[w][lane] = ss[0]; red[w][16 + lane] = ss[1]; }
    __syncthreads();
    if (t < 32) {
        float s = red[0][t] + red[1][t] + red[2][t] + red[3][t];
        invn[t] = 1.0f / fmaxf(sqrtf(s), 1e-12f);
    }
    __syncthreads();

    half_t* ehi = (type == 0) ? qhi : khi;
    half_t* elo = (type == 0) ? qlo : klo;
#pragma unroll
    for (int cg = 0; cg < 2; cg++) {
        int lloc = cg * 16 + fr;
        float sc = invn[lloc];
        size_t lrow = ((size_t)b * LL + l0 + lloc) * DD;
#pragma unroll
        for (int rg = 0; rg < 4; rg++) {
            int d0 = wr * 64 + rg * 16 + fs * 4;
            f16x4 h4, l4;
#pragma unroll
            for (int r = 0; r < 4; r++) {
                float v = acc[rg][cg][r] * sc;
                half_t h = (half_t)v;
                h4[r] = h;
                l4[r] = (half_t)(v - (float)h);
            }
            *(f16x4*)&ehi[lrow + d0] = h4;
            *(f16x4*)&elo[lrow + d0] = l4;
        }
    }
#undef LOADB
#undef WRITEB
#undef LOADA
#undef READB
#undef DOMFMA
}

// ---------------- Kernel 2: init packed max buffer
__global__ void init_packed(unsigned long long* p, int n) {
    int i = blockIdx.x * 256 + threadIdx.x;
    if (i < n) p[i] = 0ull;
}

// ---------------- Kernel 3: corr via split-3 f16 MFMA + fused column max/argmax
__global__ __launch_bounds__(256) void corr_max_mfma(const half_t* __restrict__ khi,
                                                     const half_t* __restrict__ klo,
                                                     const half_t* __restrict__ qhi,
                                                     const half_t* __restrict__ qlo,
                                                     unsigned long long* __restrict__ packed) {
    int b = blockIdx.z;
    int l0 = blockIdx.y * 64;
    int m0 = blockIdx.x * 64;
    int t = threadIdx.x;
    int w = t >> 6, lane = t & 63;
    int wr = w >> 1, wc = w & 1;
    int fr = lane & 15, fs = lane >> 4;

    const half_t* Ah = khi + (size_t)b * LL * DD;
    const half_t* Al = klo + (size_t)b * LL * DD;
    const half_t* Bh = qhi + (size_t)b * LL * DD;
    const half_t* Bl = qlo + (size_t)b * LL * DD;

    f32x4 acc[2][2];
#pragma unroll
    for (int i = 0; i < 2; i++)
#pragma unroll
        for (int j = 0; j < 2; j++) acc[i][j] = (f32x4){0.f, 0.f, 0.f, 0.f};

    for (int k0 = 0; k0 < DD; k0 += 32) {
        f16x8 a_h[2], a_l[2], b_h[2], b_l[2];
#pragma unroll
        for (int rg = 0; rg < 2; rg++) {
            size_t roff = (size_t)(l0 + wr * 32 + rg * 16 + fr) * DD + k0 + fs * 8;
            a_h[rg] = *(const f16x8*)(Ah + roff);
            a_l[rg] = *(const f16x8*)(Al + roff);
        }
#pragma unroll
        for (int cg = 0; cg < 2; cg++) {
            size_t coff = (size_t)(m0 + wc * 32 + cg * 16 + fr) * DD + k0 + fs * 8;
            b_h[cg] = *(const f16x8*)(Bh + coff);
            b_l[cg] = *(const f16x8*)(Bl + coff);
        }
#pragma unroll
        for (int rg = 0; rg < 2; rg++)
#pragma unroll
            for (int cg = 0; cg < 2; cg++) {
                acc[rg][cg] = __builtin_amdgcn_mfma_f32_16x16x32_f16(a_h[rg], b_h[cg], acc[rg][cg], 0, 0, 0);
                acc[rg][cg] = __builtin_amdgcn_mfma_f32_16x16x32_f16(a_h[rg], b_l[cg], acc[rg][cg], 0, 0, 0);
                acc[rg][cg] = __builtin_amdgcn_mfma_f32_16x16x32_f16(a_l[rg], b_h[cg], acc[rg][cg], 0, 0, 0);
            }
    }

#pragma unroll
    for (int cg = 0; cg < 2; cg++) {
        unsigned long long best = 0ull;
#pragma unroll
        for (int rg = 0; rg < 2; rg++) {
#pragma unroll
            for (int r = 0; r < 4; r++) {
                unsigned u = __float_as_uint(acc[rg][cg][r]);
                u = (u & 0x80000000u) ? ~u : (u | 0x80000000u);
                int l = l0 + wr * 32 + rg * 16 + fs * 4 + r;
                unsigned long long p = ((unsigned long long)u << 32) | (unsigned)(4095 - l);
                best = (p > best) ? p : best;
            }
        }
        unsigned long long o;
        o = __shfl_xor(best, 16); best = (o > best) ? o : best;
        o = __shfl_xor(best, 32); best = (o > best) ? o : best;
        if (lane < 16)
            atomicMax(&packed[(size_t)b * LL + m0 + wc * 32 + cg * 16 + lane], best);
    }
}

// ---------------- Kernel 4: decode packed -> S (d_out) + argmax (ws)
__global__ void decode_packed(const unsigned long long* __restrict__ packed,
                              float* __restrict__ S_out, int* __restrict__ arg) {
    int i = blockIdx.x * 256 + threadIdx.x;
    if (i < BB * LL) {
        unsigned long long p = packed[i];
        unsigned u = (unsigned)(p >> 32);
        unsigned bits = (u & 0x80000000u) ? (u & 0x7FFFFFFFu) : ~u;
        S_out[i] = __uint_as_float(bits);
        arg[i] = 4095 - (int)(unsigned)(p & 0xFFFFFFFFull);
    }
}

// ---------------- Kernel 5/7: batched 2D transpose src[R][Cc] -> dst[Cc][R]
__global__ __launch_bounds__(256) void transpose_mat(const float* __restrict__ src,
                                                     float* __restrict__ dst,
                                                     int R, int Cc) {
    __shared__ float tile[32][33];
    size_t boff = (size_t)blockIdx.z * R * Cc;
    int bx = blockIdx.x;
    int by = blockIdx.y;
    int tx = threadIdx.x & 31;
    int ty = threadIdx.x >> 5;
    const float* s = src + boff;
    float* d = dst + boff;
#pragma unroll
    for (int i = 0; i < 4; i++) {
        int r = by * 32 + ty + i * 8;
        int c = bx * 32 + tx;
        tile[ty + i * 8][tx] = s[(size_t)r * Cc + c];
    }
    __syncthreads();
#pragma unroll
    for (int i = 0; i < 4; i++) {
        int c = bx * 32 + ty + i * 8;
        int r = by * 32 + tx;
        d[(size_t)c * R + r] = tile[tx][ty + i * 8];
    }
}

// ---------------- Kernel 6: gather + fold (channel-last), one pixel per block
__global__ __launch_bounds__(256) void gather_fold(const float* __restrict__ value_t,
                                                   const int* __restrict__ arg,
                                                   float* __restrict__ T_t) {
    int b = blockIdx.y;
    int pix = blockIdx.x;
    int y = pix >> 6, x = pix & 63;
    int t = threadIdx.x;
    float2 acc = make_float2(0.f, 0.f);
    int cnty = (y == 0 || y == HH - 1) ? 2 : 3;
    int cntx = (x == 0 || x == WW - 1) ? 2 : 3;
    const int* ab = arg + b * LL;
    const float* vb = value_t + (size_t)b * LL * CC;
#pragma unroll
    for (int di = 0; di < 3; di++) {
        int my = y + 1 - di;
        if (my < 0 || my >= HH) continue;
#pragma unroll
        for (int dj = 0; dj < 3; dj++) {
            int mx = x + 1 - dj;
            if (mx < 0 || mx >= WW) continue;
            int a = ab[my * WW + mx];
            int ay = a >> 6, ax = a & 63;
            int vy = ay + di - 1, vx = ax + dj - 1;
            if (vy < 0 || vy >= HH || vx < 0 || vx >= WW) continue;
            float2 v = *(const float2*)&vb[((size_t)(vy * WW + vx)) * CC + t * 2];
            acc.x += v.x; acc.y += v.y;
        }
    }
    float inv = 1.0f / (float)(cnty * cntx);
    acc.x *= inv; acc.y *= inv;
    *(float2*)&T_t[((size_t)b * LL + pix) * CC + t * 2] = acc;
}

extern "C" void kernel_launch(void* const* d_in, const int* in_sizes, int n_in,
                              void* d_out, int out_size, void* d_ws, size_t ws_size,
                              hipStream_t stream) {
    const float* query = (const float*)d_in[0];
    const float* key   = (const float*)d_in[1];
    const float* value = (const float*)d_in[2];
    const float* Wemb  = (const float*)d_in[3];

    float* out   = (float*)d_out;
    float* S_out = out;
    float* T_out = out + BB * LL;

    char* ws = (char*)d_ws;
    size_t off = 0;
    half_t* Whi = (half_t*)(ws + off); off += (size_t)DD * CIN * 2;
    half_t* Wlo = (half_t*)(ws + off); off += (size_t)DD * CIN * 2;
    half_t* qhi = (half_t*)(ws + off); size_t emb_off = off; off += (size_t)BB * LL * DD * 2;
    half_t* qlo = (half_t*)(ws + off); off += (size_t)BB * LL * DD * 2;
    half_t* khi = (half_t*)(ws + off); off += (size_t)BB * LL * DD * 2;
    half_t* klo = (half_t*)(ws + off); off += (size_t)BB * LL * DD * 2;
    float* val_t = (float*)(ws + off); off += (size_t)BB * LL * CC * 4;
    unsigned long long* packed = (unsigned long long*)(ws + off); off += (size_t)BB * LL * 8;
    int* arg = (int*)(ws + off); off += (size_t)BB * LL * 4;
    float* T_t = (float*)(ws + emb_off);  // alias embed splits (dead after corr)

    splitW        <<<dim3((DD * CIN + 255) / 256), 256, 0, stream>>>(Wemb, Whi, Wlo);
    embed_mfma    <<<dim3(128, 4), 256, 0, stream>>>(query, key, Whi, Wlo, qhi, qlo, khi, klo);
    init_packed   <<<dim3(32), 256, 0, stream>>>(packed, BB * LL);
    corr_max_mfma <<<dim3(64, 64, 2), 256, 0, stream>>>(khi, klo, qhi, qlo, packed);
    decode_packed <<<dim3(32), 256, 0, stream>>>(packed, S_out, arg);
    transpose_mat <<<dim3(128, 16, 2), 256, 0, stream>>>(value, val_t, CC, LL);
    gather_fold   <<<dim3(4096, 2), 256, 0, stream>>>(val_t, arg, T_t);
    transpose_mat <<<dim3(16, 128, 2), 256, 0, stream>>>(T_t, T_out, LL, CC);
}

// Round 5
// 431.066 us; speedup vs baseline: 2.1135x; 1.2913x over previous
//
#include <hip/hip_runtime.h>
#include <hip/hip_bf16.h>
#include <stdint.h>
#include <math.h>

#define BB 2
#define CC 512
#define HH 64
#define WW 64
#define LL 4096
#define DD 256
#define CIN 4608   // 512*9
#define NT 144     // K steps of 32

typedef _Float16 half_t;
typedef __attribute__((ext_vector_type(8))) _Float16 f16x8;
typedef __attribute__((ext_vector_type(4))) _Float16 f16x4;
typedef __attribute__((ext_vector_type(4))) float f32x4;

// ---------------- Kernel 0: repack W into per-K-step DMA tiles, pre-swizzled.
// Tile it (32KB): for (d,ph,k): byte = it*32768 + d*128 + ((ph*64 + (k>>3)*16) ^ ((d&7)<<4)) + (k&7)*2
// DMA copies tile linearly to LDS; ds_read side applies the same XOR -> conflict-free.
__global__ __launch_bounds__(256) void splitW2(const float* __restrict__ W,
                                               char* __restrict__ Wst) {
    int i = blockIdx.x * 256 + threadIdx.x;   // NT*DD*4 = 147456 threads
    if (i >= NT * DD * 4) return;
    int it = i >> 10;                          // per it: 256 d * 4 fs
    int r  = i & 1023;
    int d  = r >> 2;
    int fs = r & 3;
    const float* src = W + (size_t)d * CIN + it * 32 + fs * 8;
    f16x8 h8, l8;
#pragma unroll
    for (int j = 0; j < 8; j++) {
        float w = src[j];
        half_t h = (half_t)w;
        h8[j] = h;
        l8[j] = (half_t)(w - (float)h);
    }
    size_t base = (size_t)it * 32768 + d * 128;
    int sw = (d & 7) << 4;
    *(f16x8*)(Wst + base + ((fs * 16) ^ sw)) = h8;
    *(f16x8*)(Wst + base + ((64 + fs * 16) ^ sw)) = l8;
}

// B LDS row: 64 halves (32 hi | 32 lo) = 128B, 8 slots of 16B, XOR swizzle by (row&7)
__device__ __forceinline__ half_t* ldsAddr(half_t* base, int r, int slot) {
    return base + r * 64 + ((slot ^ (r & 7)) << 3);
}

// gates: counted vmcnt (keep youngest 4 B-image loads in flight), drain LDS, barrier
#define GATE4() do { asm volatile("s_waitcnt vmcnt(4) lgkmcnt(0)" ::: "memory"); \
                     __builtin_amdgcn_s_barrier(); \
                     __builtin_amdgcn_sched_barrier(0); } while (0)
#define GATE0() do { asm volatile("s_waitcnt vmcnt(0) lgkmcnt(0)" ::: "memory"); \
                     __builtin_amdgcn_s_barrier(); \
                     __builtin_amdgcn_sched_barrier(0); } while (0)

// ---------------- Kernel 1: embed via f16 split-3 MFMA + fused D-norm
// C[256 d][32 l] per block; 4 waves (wave = 64d x 32l); grid (128 ltiles, 4 images)
// W tile DMA'd global->LDS per K-step (counted vmcnt pipeline); B unfold staged via regs.
__global__ __launch_bounds__(256, 2) void embed_mfma(const float* __restrict__ query,
                                                     const float* __restrict__ key,
                                                     const char* __restrict__ Wst,
                                                     half_t* __restrict__ qhi,
                                                     half_t* __restrict__ qlo,
                                                     half_t* __restrict__ khi,
                                                     half_t* __restrict__ klo) {
    __shared__ half_t sW[2][16384];     // 64 KB: W tiles [d][ph][k] swizzled
    __shared__ half_t sB[2][2048];      // 8 KB: unfold tiles
    __shared__ float red[4][32];
    __shared__ float invn[32];

    int iid = blockIdx.y;               // 0..3
    int b = iid & 1, type = iid >> 1;   // 0=query, 1=key
    const float* img = (type ? key : query) + (size_t)b * CC * LL;
    int l0 = blockIdx.x * 32;
    int y  = l0 >> 6;
    int x0 = l0 & 63;
    int t = threadIdx.x;
    int w = t >> 6;                     // wave 0..3 (d base w*64)
    int lane = t & 63;
    int wr = w;
    int fr = lane & 15;
    int fs = lane >> 4;

    // B staging state: thread stages 4 k-values for pixel x0+xB
    int xB = t & 31;
    int kcB = t >> 5;                   // k-chunk (4 k) 0..7
    int k0 = kcB * 4;
    int cS = k0 / 9;
    int offS = k0 - cS * 9;

    f32x4 acc[4][2];
#pragma unroll
    for (int rg = 0; rg < 4; rg++)
#pragma unroll
        for (int cg = 0; cg < 2; cg++) acc[rg][cg] = (f32x4){0.f, 0.f, 0.f, 0.f};

    float Bv[4];

    // exactly 4 unconditional global loads (clamped addr + value select)
#define LOADB()                                                          \
    do {                                                                 \
        int cj = cS, oj = offS;                                          \
        _Pragma("unroll")                                                \
        for (int j = 0; j < 4; j++) {                                    \
            int di = oj / 3, dj = oj - di * 3;                           \
            int yy = y + di - 1, xx = x0 + xB + dj - 1;                  \
            int vld = (yy >= 0 && yy < HH && xx >= 0 && xx < WW);        \
            int yc = yy < 0 ? 0 : (yy > HH - 1 ? HH - 1 : yy);           \
            int xc = xx < 0 ? 0 : (xx > WW - 1 ? WW - 1 : xx);           \
            float v = img[(size_t)cj * LL + yc * WW + xc];               \
            Bv[j] = vld ? v : 0.f;                                       \
            oj++; if (oj >= 9) { oj = 0; cj++; }                         \
        }                                                                \
        cS += 3; offS += 5; if (offS >= 9) { offS -= 9; cS++; }          \
    } while (0)

#define WRITEB(buf)                                                      \
    do {                                                                 \
        f16x4 h4, l4;                                                    \
        _Pragma("unroll")                                                \
        for (int j = 0; j < 4; j++) {                                    \
            half_t h = (half_t)Bv[j];                                    \
            h4[j] = h; l4[j] = (half_t)(Bv[j] - (float)h);               \
        }                                                                \
        *(f16x4*)(ldsAddr(buf, xB, kcB >> 1) + ((kcB & 1) << 2)) = h4;   \
        *(f16x4*)(ldsAddr(buf, xB, 4 + (kcB >> 1)) + ((kcB & 1) << 2)) = l4; \
    } while (0)

    // wave DMAs its own 8KB d-slice: 8 calls x (64 lanes x 16B)
#define DMAW(swbuf, itv)                                                 \
    do {                                                                 \
        const char* gsrc_ = Wst + (size_t)(itv) * 32768 + (w << 13) + (lane << 4); \
        char* ldst_ = (char*)(swbuf) + (w << 13);                        \
        _Pragma("unroll")                                                \
        for (int c = 0; c < 8; c++)                                      \
            __builtin_amdgcn_global_load_lds(                            \
                (const __attribute__((address_space(1))) void*)(gsrc_ + c * 1024), \
                (__attribute__((address_space(3))) void*)(ldst_ + c * 1024), 16, 0, 0); \
    } while (0)

#define READA(swbuf)                                                     \
    do {                                                                 \
        _Pragma("unroll")                                                \
        for (int rg = 0; rg < 4; rg++) {                                 \
            int dl = wr * 64 + rg * 16 + fr;                             \
            int sw_ = (dl & 7) << 4;                                     \
            const char* rowp = (const char*)(swbuf) + dl * 128;          \
            ah[rg] = *(const f16x8*)(rowp + ((fs * 16) ^ sw_));          \
            al[rg] = *(const f16x8*)(rowp + ((64 + fs * 16) ^ sw_));     \
        }                                                                \
    } while (0)

#define READB(buf)                                                       \
    do {                                                                 \
        _Pragma("unroll")                                                \
        for (int cg = 0; cg < 2; cg++) {                                 \
            int r = cg * 16 + fr;                                        \
            bh[cg] = *(f16x8*)ldsAddr(buf, r, fs);                       \
            bl[cg] = *(f16x8*)ldsAddr(buf, r, fs + 4);                   \
        }                                                                \
    } while (0)

#define DOMFMA()                                                         \
    do {                                                                 \
        _Pragma("unroll")                                                \
        for (int rg = 0; rg < 4; rg++)                                   \
            _Pragma("unroll")                                            \
            for (int cg = 0; cg < 2; cg++)                               \
                acc[rg][cg] = __builtin_amdgcn_mfma_f32_16x16x32_f16(ah[rg], bh[cg], acc[rg][cg], 0, 0, 0); \
        _Pragma("unroll")                                                \
        for (int rg = 0; rg < 4; rg++)                                   \
            _Pragma("unroll")                                            \
            for (int cg = 0; cg < 2; cg++) {                             \
                acc[rg][cg] = __builtin_amdgcn_mfma_f32_16x16x32_f16(ah[rg], bl[cg], acc[rg][cg], 0, 0, 0); \
                acc[rg][cg] = __builtin_amdgcn_mfma_f32_16x16x32_f16(al[rg], bh[cg], acc[rg][cg], 0, 0, 0); \
            }                                                            \
    } while (0)

    f16x8 ah[4], al[4], bh[2], bl[2];

    // ---- prologue: B(0) loads, DMA(0), write B(0), B(1) loads
    LOADB();                                  // step 0 values [4 loads]
    DMAW(&sW[0][0], 0);                       // 8 DMA calls
    __builtin_amdgcn_sched_barrier(0);
    WRITEB(&sB[0][0]);                        // auto-waits B(0) regs, DMA stays in flight
    __builtin_amdgcn_sched_barrier(0);
    LOADB();                                  // step 1 values [4 loads] -> youngest 4

    half_t* swc = &sW[0][0]; half_t* swn = &sW[1][0];
    half_t* sbc = &sB[0][0]; half_t* sbn = &sB[1][0];

    for (int it = 0; it < NT - 1; ++it) {
        GATE4();                              // W(it) in LDS, B(it) visible; 4 img loads flying
        READA(swc);
        READB(sbc);
        WRITEB(sbn);                          // B tile it+1 (auto vmcnt for its regs)
        __builtin_amdgcn_sched_barrier(0);
        DMAW(swn, it + 1);                    // 8 DMA calls (oldest VMEM group)
        __builtin_amdgcn_sched_barrier(0);
        if (it < NT - 2) LOADB();             // step it+2 values (youngest 4)
        DOMFMA();
        half_t* tp = swc; swc = swn; swn = tp;
        tp = sbc; sbc = sbn; sbn = tp;
    }
    // ---- peeled last step: full drain
    GATE0();
    READA(swc);
    READB(sbc);
    DOMFMA();

    // ---- fused normalization over d (full 256 within block)
    float ss[2] = {0.f, 0.f};
#pragma unroll
    for (int rg = 0; rg < 4; rg++)
#pragma unroll
        for (int cg = 0; cg < 2; cg++)
#pragma unroll
            for (int r = 0; r < 4; r++) ss[cg] += acc[rg][cg][r] * acc[rg][cg][r];
#pragma unroll
    for (int cg = 0; cg < 2; cg++) {
        ss[cg] += __shfl_xor(ss[cg], 16);
        ss[cg] += __shfl_xor(ss[cg], 32);
    }
    if (lane < 16) { red[w][lane] = ss[0]; red[w][16 + lane] = ss[1]; }
    __syncthreads();
    if (t < 32) {
        float s = red[0][t] + red[1][t] + red[2][t] + red[3][t];
        invn[t] = 1.0f / fmaxf(sqrtf(s), 1e-12f);
    }
    __syncthreads();

    half_t* ehi = (type == 0) ? qhi : khi;
    half_t* elo = (type == 0) ? qlo : klo;
#pragma unroll
    for (int cg = 0; cg < 2; cg++) {
        int lloc = cg * 16 + fr;
        float sc = invn[lloc];
        size_t lrow = ((size_t)b * LL + l0 + lloc) * DD;
#pragma unroll
        for (int rg = 0; rg < 4; rg++) {
            int d0 = wr * 64 + rg * 16 + fs * 4;
            f16x4 h4, l4;
#pragma unroll
            for (int r = 0; r < 4; r++) {
                float v = acc[rg][cg][r] * sc;
                half_t h = (half_t)v;
                h4[r] = h;
                l4[r] = (half_t)(v - (float)h);
            }
            *(f16x4*)&ehi[lrow + d0] = h4;
            *(f16x4*)&elo[lrow + d0] = l4;
        }
    }
#undef LOADB
#undef WRITEB
#undef DMAW
#undef READA
#undef READB
#undef DOMFMA
}

// ---------------- Kernel 2: init packed max buffer
__global__ void init_packed(unsigned long long* p, int n) {
    int i = blockIdx.x * 256 + threadIdx.x;
    if (i < n) p[i] = 0ull;
}

// ---------------- Kernel 3: corr via split-3 f16 MFMA + fused column max/argmax
__global__ __launch_bounds__(256) void corr_max_mfma(const half_t* __restrict__ khi,
                                                     const half_t* __restrict__ klo,
                                                     const half_t* __restrict__ qhi,
                                                     const half_t* __restrict__ qlo,
                                                     unsigned long long* __restrict__ packed) {
    int b = blockIdx.z;
    int l0 = blockIdx.y * 64;
    int m0 = blockIdx.x * 64;
    int t = threadIdx.x;
    int w = t >> 6, lane = t & 63;
    int wr = w >> 1, wc = w & 1;
    int fr = lane & 15, fs = lane >> 4;

    const half_t* Ah = khi + (size_t)b * LL * DD;
    const half_t* Al = klo + (size_t)b * LL * DD;
    const half_t* Bh = qhi + (size_t)b * LL * DD;
    const half_t* Bl = qlo + (size_t)b * LL * DD;

    f32x4 acc[2][2];
#pragma unroll
    for (int i = 0; i < 2; i++)
#pragma unroll
        for (int j = 0; j < 2; j++) acc[i][j] = (f32x4){0.f, 0.f, 0.f, 0.f};

    for (int k0 = 0; k0 < DD; k0 += 32) {
        f16x8 a_h[2], a_l[2], b_h[2], b_l[2];
#pragma unroll
        for (int rg = 0; rg < 2; rg++) {
            size_t roff = (size_t)(l0 + wr * 32 + rg * 16 + fr) * DD + k0 + fs * 8;
            a_h[rg] = *(const f16x8*)(Ah + roff);
            a_l[rg] = *(const f16x8*)(Al + roff);
        }
#pragma unroll
        for (int cg = 0; cg < 2; cg++) {
            size_t coff = (size_t)(m0 + wc * 32 + cg * 16 + fr) * DD + k0 + fs * 8;
            b_h[cg] = *(const f16x8*)(Bh + coff);
            b_l[cg] = *(const f16x8*)(Bl + coff);
        }
#pragma unroll
        for (int rg = 0; rg < 2; rg++)
#pragma unroll
            for (int cg = 0; cg < 2; cg++) {
                acc[rg][cg] = __builtin_amdgcn_mfma_f32_16x16x32_f16(a_h[rg], b_h[cg], acc[rg][cg], 0, 0, 0);
                acc[rg][cg] = __builtin_amdgcn_mfma_f32_16x16x32_f16(a_h[rg], b_l[cg], acc[rg][cg], 0, 0, 0);
                acc[rg][cg] = __builtin_amdgcn_mfma_f32_16x16x32_f16(a_l[rg], b_h[cg], acc[rg][cg], 0, 0, 0);
            }
    }

#pragma unroll
    for (int cg = 0; cg < 2; cg++) {
        unsigned long long best = 0ull;
#pragma unroll
        for (int rg = 0; rg < 2; rg++) {
#pragma unroll
            for (int r = 0; r < 4; r++) {
                unsigned u = __float_as_uint(acc[rg][cg][r]);
                u = (u & 0x80000000u) ? ~u : (u | 0x80000000u);
                int l = l0 + wr * 32 + rg * 16 + fs * 4 + r;
                unsigned long long p = ((unsigned long long)u << 32) | (unsigned)(4095 - l);
                best = (p > best) ? p : best;
            }
        }
        unsigned long long o;
        o = __shfl_xor(best, 16); best = (o > best) ? o : best;
        o = __shfl_xor(best, 32); best = (o > best) ? o : best;
        if (lane < 16)
            atomicMax(&packed[(size_t)b * LL + m0 + wc * 32 + cg * 16 + lane], best);
    }
}

// ---------------- Kernel 4: decode packed -> S (d_out) + argmax (ws)
__global__ void decode_packed(const unsigned long long* __restrict__ packed,
                              float* __restrict__ S_out, int* __restrict__ arg) {
    int i = blockIdx.x * 256 + threadIdx.x;
    if (i < BB * LL) {
        unsigned long long p = packed[i];
        unsigned u = (unsigned)(p >> 32);
        unsigned bits = (u & 0x80000000u) ? (u & 0x7FFFFFFFu) : ~u;
        S_out[i] = __uint_as_float(bits);
        arg[i] = 4095 - (int)(unsigned)(p & 0xFFFFFFFFull);
    }
}

// ---------------- Kernel 5/7: batched 2D transpose src[R][Cc] -> dst[Cc][R]
__global__ __launch_bounds__(256) void transpose_mat(const float* __restrict__ src,
                                                     float* __restrict__ dst,
                                                     int R, int Cc) {
    __shared__ float tile[32][33];
    size_t boff = (size_t)blockIdx.z * R * Cc;
    int bx = blockIdx.x;
    int by = blockIdx.y;
    int tx = threadIdx.x & 31;
    int ty = threadIdx.x >> 5;
    const float* s = src + boff;
    float* d = dst + boff;
#pragma unroll
    for (int i = 0; i < 4; i++) {
        int r = by * 32 + ty + i * 8;
        int c = bx * 32 + tx;
        tile[ty + i * 8][tx] = s[(size_t)r * Cc + c];
    }
    __syncthreads();
#pragma unroll
    for (int i = 0; i < 4; i++) {
        int c = bx * 32 + ty + i * 8;
        int r = by * 32 + tx;
        d[(size_t)c * R + r] = tile[tx][ty + i * 8];
    }
}

// ---------------- Kernel 6: gather + fold (channel-last), one pixel per block
__global__ __launch_bounds__(256) void gather_fold(const float* __restrict__ value_t,
                                                   const int* __restrict__ arg,
                                                   float* __restrict__ T_t) {
    int b = blockIdx.y;
    int pix = blockIdx.x;
    int y = pix >> 6, x = pix & 63;
    int t = threadIdx.x;
    float2 acc = make_float2(0.f, 0.f);
    int cnty = (y == 0 || y == HH - 1) ? 2 : 3;
    int cntx = (x == 0 || x == WW - 1) ? 2 : 3;
    const int* ab = arg + b * LL;
    const float* vb = value_t + (size_t)b * LL * CC;
#pragma unroll
    for (int di = 0; di < 3; di++) {
        int my = y + 1 - di;
        if (my < 0 || my >= HH) continue;
#pragma unroll
        for (int dj = 0; dj < 3; dj++) {
            int mx = x + 1 - dj;
            if (mx < 0 || mx >= WW) continue;
            int a = ab[my * WW + mx];
            int ay = a >> 6, ax = a & 63;
            int vy = ay + di - 1, vx = ax + dj - 1;
            if (vy < 0 || vy >= HH || vx < 0 || vx >= WW) continue;
            float2 v = *(const float2*)&vb[((size_t)(vy * WW + vx)) * CC + t * 2];
            acc.x += v.x; acc.y += v.y;
        }
    }
    float inv = 1.0f / (float)(cnty * cntx);
    acc.x *= inv; acc.y *= inv;
    *(float2*)&T_t[((size_t)b * LL + pix) * CC + t * 2] = acc;
}

extern "C" void kernel_launch(void* const* d_in, const int* in_sizes, int n_in,
                              void* d_out, int out_size, void* d_ws, size_t ws_size,
                              hipStream_t stream) {
    const float* query = (const float*)d_in[0];
    const float* key   = (const float*)d_in[1];
    const float* value = (const float*)d_in[2];
    const float* Wemb  = (const float*)d_in[3];

    float* out   = (float*)d_out;
    float* S_out = out;
    float* T_out = out + BB * LL;

    char* ws = (char*)d_ws;
    size_t off = 0;
    char*  Wst = ws + off; off += (size_t)NT * 32768;                       // 4.72 MB
    half_t* qhi = (half_t*)(ws + off); size_t emb_off = off; off += (size_t)BB * LL * DD * 2;
    half_t* qlo = (half_t*)(ws + off); off += (size_t)BB * LL * DD * 2;
    half_t* khi = (half_t*)(ws + off); off += (size_t)BB * LL * DD * 2;
    half_t* klo = (half_t*)(ws + off); off += (size_t)BB * LL * DD * 2;
    float* val_t = (float*)(ws + off); off += (size_t)BB * LL * CC * 4;
    unsigned long long* packed = (unsigned long long*)(ws + off); off += (size_t)BB * LL * 8;
    int* arg = (int*)(ws + off); off += (size_t)BB * LL * 4;
    float* T_t = (float*)(ws + emb_off);  // alias embed splits (dead after corr)

    splitW2       <<<dim3(576), 256, 0, stream>>>(Wemb, Wst);
    embed_mfma    <<<dim3(128, 4), 256, 0, stream>>>(query, key, Wst, qhi, qlo, khi, klo);
    init_packed   <<<dim3(32), 256, 0, stream>>>(packed, BB * LL);
    corr_max_mfma <<<dim3(64, 64, 2), 256, 0, stream>>>(khi, klo, qhi, qlo, packed);
    decode_packed <<<dim3(32), 256, 0, stream>>>(packed, S_out, arg);
    transpose_mat <<<dim3(128, 16, 2), 256, 0, stream>>>(value, val_t, CC, LL);
    gather_fold   <<<dim3(4096, 2), 256, 0, stream>>>(val_t, arg, T_t);
    transpose_mat <<<dim3(16, 128, 2), 256, 0, stream>>>(T_t, T_out, LL, CC);
}

// Round 6
// 255.329 us; speedup vs baseline: 3.5681x; 1.6883x over previous
//
#include <hip/hip_runtime.h>
#include <hip/hip_bf16.h>
#include <stdint.h>
#include <math.h>

#define BB 2
#define CC 512
#define HH 64
#define WW 64
#define LL 4096
#define DD 256
#define CIN 4608   // 512*9
#define NT 144     // K steps of 32

typedef _Float16 half_t;
typedef __attribute__((ext_vector_type(8))) _Float16 f16x8;
typedef __attribute__((ext_vector_type(4))) _Float16 f16x4;
typedef __attribute__((ext_vector_type(4))) float f32x4;

// ---------------- Kernel 0: repack W into per-K-step DMA tiles, pre-swizzled.
__global__ __launch_bounds__(256) void splitW2(const float* __restrict__ W,
                                               char* __restrict__ Wst) {
    int i = blockIdx.x * 256 + threadIdx.x;   // NT*DD*4 = 147456 threads
    if (i >= NT * DD * 4) return;
    int it = i >> 10;                          // per it: 256 d * 4 fs
    int r  = i & 1023;
    int d  = r >> 2;
    int fs = r & 3;
    const float* src = W + (size_t)d * CIN + it * 32 + fs * 8;
    f16x8 h8, l8;
#pragma unroll
    for (int j = 0; j < 8; j++) {
        float w = src[j];
        half_t h = (half_t)w;
        h8[j] = h;
        l8[j] = (half_t)(w - (float)h);
    }
    size_t base = (size_t)it * 32768 + d * 128;
    int sw = (d & 7) << 4;
    *(f16x8*)(Wst + base + ((fs * 16) ^ sw)) = h8;
    *(f16x8*)(Wst + base + ((64 + fs * 16) ^ sw)) = l8;
}

// B LDS row: 64 halves (32 hi | 32 lo) = 128B, 8 slots of 16B, XOR swizzle by (row&7)
__device__ __forceinline__ half_t* ldsAddr(half_t* base, int r, int slot) {
    return base + r * 64 + ((slot ^ (r & 7)) << 3);
}

// gates: counted vmcnt (keep youngest 4 B-image loads in flight), drain LDS, barrier
#define GATE4() do { asm volatile("s_waitcnt vmcnt(4) lgkmcnt(0)" ::: "memory"); \
                     __builtin_amdgcn_s_barrier(); \
                     __builtin_amdgcn_sched_barrier(0); } while (0)
#define GATE0() do { asm volatile("s_waitcnt vmcnt(0) lgkmcnt(0)" ::: "memory"); \
                     __builtin_amdgcn_s_barrier(); \
                     __builtin_amdgcn_sched_barrier(0); } while (0)

// ---------------- Kernel 1: embed via f16 split-3 MFMA + fused D-norm
// Epilogue writes corr-ready layout: per row l (1024 B): 8 it-blocks of 128 B,
// each = hi/lo 16B chunks, chunk byte-offset XOR'd by ((l&7)<<4).
__global__ __launch_bounds__(256, 2) void embed_mfma(const float* __restrict__ query,
                                                     const float* __restrict__ key,
                                                     const char* __restrict__ Wst,
                                                     char* __restrict__ qemb,
                                                     char* __restrict__ kemb) {
    __shared__ half_t sW[2][16384];     // 64 KB: W tiles swizzled
    __shared__ half_t sB[2][2048];      // 8 KB: unfold tiles
    __shared__ float red[4][32];
    __shared__ float invn[32];

    int iid = blockIdx.y;               // 0..3
    int b = iid & 1, type = iid >> 1;   // 0=query, 1=key
    const float* img = (type ? key : query) + (size_t)b * CC * LL;
    int l0 = blockIdx.x * 32;
    int y  = l0 >> 6;
    int x0 = l0 & 63;
    int t = threadIdx.x;
    int w = t >> 6;                     // wave 0..3 (d base w*64)
    int lane = t & 63;
    int wr = w;
    int fr = lane & 15;
    int fs = lane >> 4;

    int xB = t & 31;
    int kcB = t >> 5;                   // k-chunk (4 k) 0..7
    int k0 = kcB * 4;
    int cS = k0 / 9;
    int offS = k0 - cS * 9;

    f32x4 acc[4][2];
#pragma unroll
    for (int rg = 0; rg < 4; rg++)
#pragma unroll
        for (int cg = 0; cg < 2; cg++) acc[rg][cg] = (f32x4){0.f, 0.f, 0.f, 0.f};

    float Bv[4];

#define LOADB()                                                          \
    do {                                                                 \
        int cj = cS, oj = offS;                                          \
        _Pragma("unroll")                                                \
        for (int j = 0; j < 4; j++) {                                    \
            int di = oj / 3, dj = oj - di * 3;                           \
            int yy = y + di - 1, xx = x0 + xB + dj - 1;                  \
            int vld = (yy >= 0 && yy < HH && xx >= 0 && xx < WW);        \
            int yc = yy < 0 ? 0 : (yy > HH - 1 ? HH - 1 : yy);           \
            int xc = xx < 0 ? 0 : (xx > WW - 1 ? WW - 1 : xx);           \
            float v = img[(size_t)cj * LL + yc * WW + xc];               \
            Bv[j] = vld ? v : 0.f;                                       \
            oj++; if (oj >= 9) { oj = 0; cj++; }                         \
        }                                                                \
        cS += 3; offS += 5; if (offS >= 9) { offS -= 9; cS++; }          \
    } while (0)

#define WRITEB(buf)                                                      \
    do {                                                                 \
        f16x4 h4, l4;                                                    \
        _Pragma("unroll")                                                \
        for (int j = 0; j < 4; j++) {                                    \
            half_t h = (half_t)Bv[j];                                    \
            h4[j] = h; l4[j] = (half_t)(Bv[j] - (float)h);               \
        }                                                                \
        *(f16x4*)(ldsAddr(buf, xB, kcB >> 1) + ((kcB & 1) << 2)) = h4;   \
        *(f16x4*)(ldsAddr(buf, xB, 4 + (kcB >> 1)) + ((kcB & 1) << 2)) = l4; \
    } while (0)

#define DMAW(swbuf, itv)                                                 \
    do {                                                                 \
        const char* gsrc_ = Wst + (size_t)(itv) * 32768 + (w << 13) + (lane << 4); \
        char* ldst_ = (char*)(swbuf) + (w << 13);                        \
        _Pragma("unroll")                                                \
        for (int c = 0; c < 8; c++)                                      \
            __builtin_amdgcn_global_load_lds(                            \
                (const __attribute__((address_space(1))) void*)(gsrc_ + c * 1024), \
                (__attribute__((address_space(3))) void*)(ldst_ + c * 1024), 16, 0, 0); \
    } while (0)

#define READA(swbuf)                                                     \
    do {                                                                 \
        _Pragma("unroll")                                                \
        for (int rg = 0; rg < 4; rg++) {                                 \
            int dl = wr * 64 + rg * 16 + fr;                             \
            int sw_ = (dl & 7) << 4;                                     \
            const char* rowp = (const char*)(swbuf) + dl * 128;          \
            ah[rg] = *(const f16x8*)(rowp + ((fs * 16) ^ sw_));          \
            al[rg] = *(const f16x8*)(rowp + ((64 + fs * 16) ^ sw_));     \
        }                                                                \
    } while (0)

#define READB(buf)                                                       \
    do {                                                                 \
        _Pragma("unroll")                                                \
        for (int cg = 0; cg < 2; cg++) {                                 \
            int r = cg * 16 + fr;                                        \
            bh[cg] = *(f16x8*)ldsAddr(buf, r, fs);                       \
            bl[cg] = *(f16x8*)ldsAddr(buf, r, fs + 4);                   \
        }                                                                \
    } while (0)

#define DOMFMA()                                                         \
    do {                                                                 \
        _Pragma("unroll")                                                \
        for (int rg = 0; rg < 4; rg++)                                   \
            _Pragma("unroll")                                            \
            for (int cg = 0; cg < 2; cg++)                               \
                acc[rg][cg] = __builtin_amdgcn_mfma_f32_16x16x32_f16(ah[rg], bh[cg], acc[rg][cg], 0, 0, 0); \
        _Pragma("unroll")                                                \
        for (int rg = 0; rg < 4; rg++)                                   \
            _Pragma("unroll")                                            \
            for (int cg = 0; cg < 2; cg++) {                             \
                acc[rg][cg] = __builtin_amdgcn_mfma_f32_16x16x32_f16(ah[rg], bl[cg], acc[rg][cg], 0, 0, 0); \
                acc[rg][cg] = __builtin_amdgcn_mfma_f32_16x16x32_f16(al[rg], bh[cg], acc[rg][cg], 0, 0, 0); \
            }                                                            \
    } while (0)

    f16x8 ah[4], al[4], bh[2], bl[2];

    LOADB();
    DMAW(&sW[0][0], 0);
    __builtin_amdgcn_sched_barrier(0);
    WRITEB(&sB[0][0]);
    __builtin_amdgcn_sched_barrier(0);
    LOADB();

    half_t* swc = &sW[0][0]; half_t* swn = &sW[1][0];
    half_t* sbc = &sB[0][0]; half_t* sbn = &sB[1][0];

    for (int it = 0; it < NT - 1; ++it) {
        GATE4();
        READA(swc);
        READB(sbc);
        WRITEB(sbn);
        __builtin_amdgcn_sched_barrier(0);
        DMAW(swn, it + 1);
        __builtin_amdgcn_sched_barrier(0);
        if (it < NT - 2) LOADB();
        DOMFMA();
        half_t* tp = swc; swc = swn; swn = tp;
        tp = sbc; sbc = sbn; sbn = tp;
    }
    GATE0();
    READA(swc);
    READB(sbc);
    DOMFMA();

    // ---- fused normalization over d (full 256 within block)
    float ss[2] = {0.f, 0.f};
#pragma unroll
    for (int rg = 0; rg < 4; rg++)
#pragma unroll
        for (int cg = 0; cg < 2; cg++)
#pragma unroll
            for (int r = 0; r < 4; r++) ss[cg] += acc[rg][cg][r] * acc[rg][cg][r];
#pragma unroll
    for (int cg = 0; cg < 2; cg++) {
        ss[cg] += __shfl_xor(ss[cg], 16);
        ss[cg] += __shfl_xor(ss[cg], 32);
    }
    if (lane < 16) { red[w][lane] = ss[0]; red[w][16 + lane] = ss[1]; }
    __syncthreads();
    if (t < 32) {
        float s = red[0][t] + red[1][t] + red[2][t] + red[3][t];
        invn[t] = 1.0f / fmaxf(sqrtf(s), 1e-12f);
    }
    __syncthreads();

    // ---- epilogue: corr-ready swizzled layout
    char* e = (type == 0) ? qemb : kemb;
#pragma unroll
    for (int cg = 0; cg < 2; cg++) {
        int lloc = cg * 16 + fr;
        float sc = invn[lloc];
        int l = l0 + lloc;
        char* rowp = e + ((size_t)b * LL + l) * 1024;
        int swb = (l & 7) << 4;
#pragma unroll
        for (int rg = 0; rg < 4; rg++) {
            int d0 = wr * 64 + rg * 16 + fs * 4;
            f16x4 h4, l4;
#pragma unroll
            for (int r = 0; r < 4; r++) {
                float v = acc[rg][cg][r] * sc;
                half_t h = (half_t)v;
                h4[r] = h;
                l4[r] = (half_t)(v - (float)h);
            }
            int itb = d0 >> 5;
            int fsc = (d0 >> 3) & 3;
            int sub = (d0 & 7) * 2;
            *(f16x4*)(rowp + itb * 128 + ((fsc * 16) ^ swb) + sub) = h4;
            *(f16x4*)(rowp + itb * 128 + ((64 + fsc * 16) ^ swb) + sub) = l4;
        }
    }
#undef LOADB
#undef WRITEB
#undef DMAW
#undef READA
#undef READB
#undef DOMFMA
}

// ---------------- Kernel 2: init packed max buffer
__global__ void init_packed(unsigned long long* p, int n) {
    int i = blockIdx.x * 256 + threadIdx.x;
    if (i < n) p[i] = 0ull;
}

// ---------------- Kernel 3: corr via LDS-staged split-3 MFMA + fused max/argmax
// 128l x 128m tile per block; 4 waves (64l x 64m each); K=256 in 8 steps, dbuf DMA.
__global__ __launch_bounds__(256, 2) void corr_max_mfma(const char* __restrict__ kemb,
                                                        const char* __restrict__ qemb,
                                                        unsigned long long* __restrict__ packed) {
    __shared__ char sA[2][16384];
    __shared__ char sBq[2][16384];

    int b  = blockIdx.z;
    int l0 = blockIdx.y * 128;
    int m0 = blockIdx.x * 128;
    int t  = threadIdx.x;
    int w = t >> 6, lane = t & 63;
    int wr = w >> 1, wc = w & 1;        // wave: l base wr*64, m base wc*64
    int fr = lane & 15, fs = lane >> 4;

    const char* Abase = kemb + ((size_t)b * LL + l0) * 1024;
    const char* Bbase = qemb + ((size_t)b * LL + m0) * 1024;

    f32x4 acc[4][4];
#pragma unroll
    for (int i = 0; i < 4; i++)
#pragma unroll
        for (int j = 0; j < 4; j++) acc[i][j] = (f32x4){0.f, 0.f, 0.f, 0.f};

#define DMA2(bufi, itv)                                                   \
    do {                                                                  \
        _Pragma("unroll")                                                 \
        for (int c = 0; c < 4; c++) {                                     \
            int idx = c * 4096 + t * 16;                                  \
            int row = idx >> 7, offb = idx & 127;                         \
            __builtin_amdgcn_global_load_lds(                             \
                (const __attribute__((address_space(1))) void*)(Abase + (size_t)row * 1024 + (itv) * 128 + offb), \
                (__attribute__((address_space(3))) void*)(&sA[bufi][idx]), 16, 0, 0); \
        }                                                                 \
        _Pragma("unroll")                                                 \
        for (int c = 0; c < 4; c++) {                                     \
            int idx = c * 4096 + t * 16;                                  \
            int row = idx >> 7, offb = idx & 127;                         \
            __builtin_amdgcn_global_load_lds(                             \
                (const __attribute__((address_space(1))) void*)(Bbase + (size_t)row * 1024 + (itv) * 128 + offb), \
                (__attribute__((address_space(3))) void*)(&sBq[bufi][idx]), 16, 0, 0); \
        }                                                                 \
    } while (0)

    DMA2(0, 0);

    f16x8 ah[4], al[4], bh[4], bl[4];
    for (int it = 0; it < 8; ++it) {
        asm volatile("s_waitcnt vmcnt(0) lgkmcnt(0)" ::: "memory");
        __builtin_amdgcn_s_barrier();
        __builtin_amdgcn_sched_barrier(0);
        if (it < 7) DMA2((it + 1) & 1, it + 1);
        __builtin_amdgcn_sched_barrier(0);
        const char* sa = sA[it & 1];
        const char* sb = sBq[it & 1];
#pragma unroll
        for (int rg = 0; rg < 4; rg++) {
            int r = wr * 64 + rg * 16 + fr;
            const char* rp = sa + r * 128;
            int sw_ = (r & 7) << 4;
            ah[rg] = *(const f16x8*)(rp + ((fs * 16) ^ sw_));
            al[rg] = *(const f16x8*)(rp + ((64 + fs * 16) ^ sw_));
        }
#pragma unroll
        for (int cg = 0; cg < 4; cg++) {
            int r = wc * 64 + cg * 16 + fr;
            const char* rp = sb + r * 128;
            int sw_ = (r & 7) << 4;
            bh[cg] = *(const f16x8*)(rp + ((fs * 16) ^ sw_));
            bl[cg] = *(const f16x8*)(rp + ((64 + fs * 16) ^ sw_));
        }
#pragma unroll
        for (int rg = 0; rg < 4; rg++)
#pragma unroll
            for (int cg = 0; cg < 4; cg++)
                acc[rg][cg] = __builtin_amdgcn_mfma_f32_16x16x32_f16(ah[rg], bh[cg], acc[rg][cg], 0, 0, 0);
#pragma unroll
        for (int rg = 0; rg < 4; rg++)
#pragma unroll
            for (int cg = 0; cg < 4; cg++) {
                acc[rg][cg] = __builtin_amdgcn_mfma_f32_16x16x32_f16(ah[rg], bl[cg], acc[rg][cg], 0, 0, 0);
                acc[rg][cg] = __builtin_amdgcn_mfma_f32_16x16x32_f16(al[rg], bh[cg], acc[rg][cg], 0, 0, 0);
            }
    }
#undef DMA2

    // column max per m (C: col m = fr, row l = fs*4+r)
#pragma unroll
    for (int cg = 0; cg < 4; cg++) {
        unsigned long long best = 0ull;
#pragma unroll
        for (int rg = 0; rg < 4; rg++) {
#pragma unroll
            for (int r = 0; r < 4; r++) {
                unsigned u = __float_as_uint(acc[rg][cg][r]);
                u = (u & 0x80000000u) ? ~u : (u | 0x80000000u);
                int l = l0 + wr * 64 + rg * 16 + fs * 4 + r;
                unsigned long long p = ((unsigned long long)u << 32) | (unsigned)(4095 - l);
                best = (p > best) ? p : best;
            }
        }
        unsigned long long o;
        o = __shfl_xor(best, 16); best = (o > best) ? o : best;
        o = __shfl_xor(best, 32); best = (o > best) ? o : best;
        if (lane < 16)
            atomicMax(&packed[(size_t)b * LL + m0 + wc * 64 + cg * 16 + lane], best);
    }
}

// ---------------- Kernel 4: decode packed -> S (d_out) + argmax (ws)
__global__ void decode_packed(const unsigned long long* __restrict__ packed,
                              float* __restrict__ S_out, int* __restrict__ arg) {
    int i = blockIdx.x * 256 + threadIdx.x;
    if (i < BB * LL) {
        unsigned long long p = packed[i];
        unsigned u = (unsigned)(p >> 32);
        unsigned bits = (u & 0x80000000u) ? (u & 0x7FFFFFFFu) : ~u;
        S_out[i] = __uint_as_float(bits);
        arg[i] = 4095 - (int)(unsigned)(p & 0xFFFFFFFFull);
    }
}

// ---------------- Kernel 5/7: batched 2D transpose src[R][Cc] -> dst[Cc][R]
__global__ __launch_bounds__(256) void transpose_mat(const float* __restrict__ src,
                                                     float* __restrict__ dst,
                                                     int R, int Cc) {
    __shared__ float tile[32][33];
    size_t boff = (size_t)blockIdx.z * R * Cc;
    int bx = blockIdx.x;
    int by = blockIdx.y;
    int tx = threadIdx.x & 31;
    int ty = threadIdx.x >> 5;
    const float* s = src + boff;
    float* d = dst + boff;
#pragma unroll
    for (int i = 0; i < 4; i++) {
        int r = by * 32 + ty + i * 8;
        int c = bx * 32 + tx;
        tile[ty + i * 8][tx] = s[(size_t)r * Cc + c];
    }
    __syncthreads();
#pragma unroll
    for (int i = 0; i < 4; i++) {
        int c = bx * 32 + ty + i * 8;
        int r = by * 32 + tx;
        d[(size_t)c * R + r] = tile[tx][ty + i * 8];
    }
}

// ---------------- Kernel 6: gather + fold (channel-last), one pixel per block
__global__ __launch_bounds__(256) void gather_fold(const float* __restrict__ value_t,
                                                   const int* __restrict__ arg,
                                                   float* __restrict__ T_t) {
    int b = blockIdx.y;
    int pix = blockIdx.x;
    int y = pix >> 6, x = pix & 63;
    int t = threadIdx.x;
    float2 acc = make_float2(0.f, 0.f);
    int cnty = (y == 0 || y == HH - 1) ? 2 : 3;
    int cntx = (x == 0 || x == WW - 1) ? 2 : 3;
    const int* ab = arg + b * LL;
    const float* vb = value_t + (size_t)b * LL * CC;
#pragma unroll
    for (int di = 0; di < 3; di++) {
        int my = y + 1 - di;
        if (my < 0 || my >= HH) continue;
#pragma unroll
        for (int dj = 0; dj < 3; dj++) {
            int mx = x + 1 - dj;
            if (mx < 0 || mx >= WW) continue;
            int a = ab[my * WW + mx];
            int ay = a >> 6, ax = a & 63;
            int vy = ay + di - 1, vx = ax + dj - 1;
            if (vy < 0 || vy >= HH || vx < 0 || vx >= WW) continue;
            float2 v = *(const float2*)&vb[((size_t)(vy * WW + vx)) * CC + t * 2];
            acc.x += v.x; acc.y += v.y;
        }
    }
    float inv = 1.0f / (float)(cnty * cntx);
    acc.x *= inv; acc.y *= inv;
    *(float2*)&T_t[((size_t)b * LL + pix) * CC + t * 2] = acc;
}

extern "C" void kernel_launch(void* const* d_in, const int* in_sizes, int n_in,
                              void* d_out, int out_size, void* d_ws, size_t ws_size,
                              hipStream_t stream) {
    const float* query = (const float*)d_in[0];
    const float* key   = (const float*)d_in[1];
    const float* value = (const float*)d_in[2];
    const float* Wemb  = (const float*)d_in[3];

    float* out   = (float*)d_out;
    float* S_out = out;
    float* T_out = out + BB * LL;

    char* ws = (char*)d_ws;
    size_t off = 0;
    char* Wst  = ws + off; off += (size_t)NT * 32768;                 // 4.72 MB (dead after embed)
    char* qemb = ws + off; off += (size_t)BB * LL * 1024;             // 8.39 MB (dead after corr)
    char* kemb = ws + off; off += (size_t)BB * LL * 1024;             // 8.39 MB (dead after corr)
    float* val_t = (float*)(ws + off); off += (size_t)BB * LL * CC * 4;  // 16.78 MB
    unsigned long long* packed = (unsigned long long*)(ws + off); off += (size_t)BB * LL * 8;
    int* arg = (int*)(ws + off); off += (size_t)BB * LL * 4;
    float* T_t = (float*)ws;  // alias Wst+qemb+part of kemb (16.78 MB, all dead by then)

    splitW2       <<<dim3(576), 256, 0, stream>>>(Wemb, Wst);
    embed_mfma    <<<dim3(128, 4), 256, 0, stream>>>(query, key, Wst, qemb, kemb);
    init_packed   <<<dim3(32), 256, 0, stream>>>(packed, BB * LL);
    corr_max_mfma <<<dim3(32, 32, 2), 256, 0, stream>>>(kemb, qemb, packed);
    decode_packed <<<dim3(32), 256, 0, stream>>>(packed, S_out, arg);
    transpose_mat <<<dim3(128, 16, 2), 256, 0, stream>>>(value, val_t, CC, LL);
    gather_fold   <<<dim3(4096, 2), 256, 0, stream>>>(val_t, arg, T_t);
    transpose_mat <<<dim3(16, 128, 2), 256, 0, stream>>>(T_t, T_out, LL, CC);
}